// Round 13
// baseline (90.199 us; speedup 1.0000x reference)
//
#include <hip/hip_runtime.h>

#define B_N 4096
#define D_IN 1024
#define D_F 256
#define MK 80
#define LOG2PI 1.8378770664093453f
#define XP_S 72  // padded LDS row stride (bf16 elems)

typedef float f32x4 __attribute__((ext_vector_type(4)));
typedef short bf16x8 __attribute__((ext_vector_type(8)));
typedef float float4_ __attribute__((ext_vector_type(4)));
typedef unsigned int u32x4 __attribute__((ext_vector_type(4)));
typedef unsigned short u16x8 __attribute__((ext_vector_type(8)));

__device__ __forceinline__ unsigned short f2bf(float f) {
    unsigned u = __float_as_uint(f);
    u += 0x7fffu + ((u >> 16) & 1u);
    return (unsigned short)(u >> 16);
}
__device__ __forceinline__ float bf2f(unsigned short h) {
    return __uint_as_float(((unsigned)h) << 16);
}
__device__ __forceinline__ void gload_lds16(const void* g, void* l) {
    __builtin_amdgcn_global_load_lds((const __attribute__((address_space(1))) void*)g,
                                     (__attribute__((address_space(3))) void*)l, 16, 0, 0);
}
__device__ __forceinline__ bf16x8 pack8(float4_ a, float4_ b) {
    bf16x8 r;
    r[0] = (short)f2bf(a.x); r[1] = (short)f2bf(a.y);
    r[2] = (short)f2bf(a.z); r[3] = (short)f2bf(a.w);
    r[4] = (short)f2bf(b.x); r[5] = (short)f2bf(b.y);
    r[6] = (short)f2bf(b.z); r[7] = (short)f2bf(b.w);
    return r;
}

// ---------------- K_pre: W-transpose, stats, covs->bf16, diag-block Neumann ----
// grid 544: [0,64) W-transpose, [64,144) stats, [144,224) off-diag covsb (plain
// bf16 L blocks), [224,544) diag-block inversion (mk,I) via Neumann + MFMA.
// covsb per mk: [0..5] off-diag L(I,K) K<I at idx I*(I-1)/2+K; [6..9] Dinv.
__global__ __launch_bounds__(256) void k_pre(const float* __restrict__ W,
                                             const float* __restrict__ covs,
                                             const float* __restrict__ wts,
                                             unsigned short* __restrict__ wt,
                                             float* __restrict__ wmix,
                                             float* __restrict__ ldet,
                                             unsigned short* __restrict__ covsb) {
    int bx = blockIdx.x, tid = threadIdx.x;
    if (bx < 64) {
        __shared__ unsigned short t[64][65];
        int k0 = (bx >> 2) * 64, n0 = (bx & 3) * 64;
        int r = tid / 64, c = tid % 64;
        #pragma unroll
        for (int rr = r; rr < 64; rr += 4)
            t[rr][c] = f2bf(W[(size_t)(k0 + rr) * D_F + n0 + c]);
        __syncthreads();
        #pragma unroll
        for (int rr = r; rr < 64; rr += 4)
            wt[(size_t)(n0 + rr) * D_IN + k0 + c] = t[c][rr];
    } else if (bx < 144) {
        if (tid < 64) {
            int mk = bx - 64;
            int l = tid;
            const float* Lm = covs + (size_t)mk * D_F * D_F;
            float s = 0.0f;
            for (int i = l; i < D_F; i += 64) s += logf(Lm[(size_t)i * D_F + i]);
            for (int off = 32; off; off >>= 1) s += __shfl_down(s, off);
            if (l == 0) {
                ldet[mk] = s;
                int m = mk / 8, k = mk % 8;
                float mx = -1e30f;
                for (int j = 0; j < 8; j++) mx = fmaxf(mx, wts[m * 8 + j]);
                float sum = 0.0f;
                for (int j = 0; j < 8; j++) sum += expf(wts[m * 8 + j] - mx);
                wmix[mk] = expf(wts[m * 8 + k] - mx) / sum;
            }
        }
    } else if (bx < 224) {
        // covs off-diag lower blocks -> plain bf16: (I,K), K<I, idx = I*(I-1)/2+K
        int mk = bx - 144;
        const float* Cm = covs + (size_t)mk * D_F * D_F;
        unsigned short* Cb = covsb + (size_t)mk * 10 * 4096;
        #pragma unroll
        for (int I = 1; I < 4; ++I)
            for (int K = 0; K < I; ++K) {
                int idx = (I * (I - 1)) / 2 + K;
                for (int t4 = tid; t4 < 1024; t4 += 256) {
                    int r = t4 >> 4, kq = t4 & 15;
                    float4_ v = *(const float4_*)&Cm[(size_t)(I * 64 + r) * D_F
                                                     + K * 64 + kq * 4];
                    ushort4 o;
                    o.x = f2bf(v.x); o.y = f2bf(v.y); o.z = f2bf(v.z); o.w = f2bf(v.w);
                    *(ushort4*)&Cb[(size_t)idx * 4096 + r * 64 + kq * 4] = o;
                }
            }
    } else {
        // diag-block inverse via Neumann: Dinv = (I - X + X^2 - X^3 + X^4) D^-1,
        // X = D^-1 strict_lower(Ldiag), ||X|| ~ 0.08 -> truncation ~3e-6.
        int b = bx - 224;
        int mk = b >> 2, I = b & 3;
        int i0 = I * 64;
        __shared__ float rl[64];
        __shared__ unsigned short X[64][XP_S];
        __shared__ unsigned short Yt[2][64][XP_S];
        int w = tid >> 6, l = tid & 63;
        const float* Cm = covs + (size_t)mk * D_F * D_F;
        if (tid < 64) rl[tid] = 1.0f / Cm[(size_t)(i0 + tid) * D_F + i0 + tid];
        __syncthreads();
        // build X (row-scaled strict lower) directly in LDS
        for (int t4 = tid; t4 < 1024; t4 += 256) {
            int r = t4 >> 4, kq = t4 & 15;
            float4_ v = *(const float4_*)&Cm[(size_t)(i0 + r) * D_F + i0 + kq * 4];
            float ri = rl[r];
            int base = kq * 4;
            ushort4 o;
            o.x = (base     < r) ? f2bf(v.x * ri) : (unsigned short)0;
            o.y = (base + 1 < r) ? f2bf(v.y * ri) : (unsigned short)0;
            o.z = (base + 2 < r) ? f2bf(v.z * ri) : (unsigned short)0;
            o.w = (base + 3 < r) ? f2bf(v.w * ri) : (unsigned short)0;
            *(ushort4*)&X[r][base] = o;
        }
        __syncthreads();
        // T1 = I - X (transposed): Yt[0][j][i] = delta_ij - X[i][j]
        for (int t = tid; t < 4096; t += 256) {
            int j = t >> 6, i = t & 63;
            unsigned short xv = X[i][j];
            Yt[0][j][i] = (i == j) ? (unsigned short)0x3F80
                                   : (unsigned short)(xv ^ 0x8000u);
        }
        __syncthreads();
        int cur = 0;
        for (int it = 0; it < 3; ++it) {
            bf16x8 a0 = *(const bf16x8*)&Yt[cur][16 * w + (l & 15)][(l >> 4) * 8];
            bf16x8 a1 = *(const bf16x8*)&Yt[cur][16 * w + (l & 15)][32 + (l >> 4) * 8];
            f32x4 acc[4] = {{0, 0, 0, 0}, {0, 0, 0, 0}, {0, 0, 0, 0}, {0, 0, 0, 0}};
            #pragma unroll
            for (int ni = 0; ni < 4; ++ni) {
                bf16x8 b0 = *(const bf16x8*)&X[ni * 16 + (l & 15)][(l >> 4) * 8];
                bf16x8 b1 = *(const bf16x8*)&X[ni * 16 + (l & 15)][32 + (l >> 4) * 8];
                acc[ni] = __builtin_amdgcn_mfma_f32_16x16x32_bf16(a0, b0, acc[ni], 0, 0, 0);
                acc[ni] = __builtin_amdgcn_mfma_f32_16x16x32_bf16(a1, b1, acc[ni], 0, 0, 0);
            }
            #pragma unroll
            for (int ni = 0; ni < 4; ++ni)
                #pragma unroll
                for (int q = 0; q < 4; ++q) {
                    int i = ni * 16 + (l & 15);
                    int j = 16 * w + (l >> 4) * 4 + q;
                    float v = ((i == j) ? 1.0f : 0.0f) - acc[ni][q];
                    Yt[cur ^ 1][j][i] = f2bf(v);
                }
            __syncthreads();
            cur ^= 1;
        }
        // Dinv[r][c] = Yt[cur][c][r] * rl[c] -> covsb slot [6+I]
        unsigned short* Xg = covsb + ((size_t)mk * 10 + 6 + I) * 4096;
        for (int t = tid; t < 4096; t += 256) {
            int r = t >> 6, c = t & 63;
            Xg[t] = f2bf(bf2f(Yt[cur][c][r]) * rl[c]);
        }
    }
}

// ---------------- K5b: column panels of Linv via blocked MFMA + cvec partial ---
__global__ __launch_bounds__(256) void k_inv_panel(
        const unsigned short* __restrict__ covsb,
        const float* __restrict__ means,
        unsigned short* __restrict__ linv,
        float* __restrict__ cpart) {
    int mk = blockIdx.x, J = blockIdx.y;
    int jc0 = J * 64;
    __shared__ unsigned short Xp[4][64][XP_S];  // 73.7 KB
    __shared__ unsigned short Sb[64][XP_S];     // 9.2 KB
    __shared__ float muS[64];
    int tid = threadIdx.x, w = tid >> 6, l = tid & 63;
    const unsigned short* Cb = covsb + (size_t)mk * 10 * 4096;   // off-diag [0..5]
    const unsigned short* Dmk = Cb + 6 * 4096;                   // Dinv [6..9]
    unsigned short* Lout = linv + (size_t)mk * D_F * D_F;

    for (int t = tid; t < jc0 * 8; t += 256) {
        int r = t >> 3, s = t & 7;
        ((u32x4*)(Lout + (size_t)r * D_F + jc0))[s] = (u32x4){0, 0, 0, 0};
    }
    const unsigned short* DJ = Dmk + J * 4096;
    for (int t = tid; t < 4096; t += 256) {
        int r = t >> 6, c = t & 63;
        Xp[J][c][r] = DJ[t];
    }
    for (int t = tid; t < 512; t += 256) {
        int r = t >> 3, s = t & 7;
        ((u32x4*)(Lout + (size_t)(jc0 + r) * D_F + jc0))[s] = ((const u32x4*)(DJ + r * 64))[s];
    }
    __syncthreads();

    for (int I = J + 1; I < 4; ++I) {
        f32x4 acc[4] = {};
        for (int K = J; K < I; ++K) {
            const unsigned short* CB = Cb + (size_t)((I * (I - 1)) / 2 + K) * 4096;
            #pragma unroll
            for (int kb = 0; kb < 2; ++kb) {
                bf16x8 af = *(const bf16x8*)&Xp[K][w * 16 + (l & 15)][kb * 32 + (l >> 4) * 8];
                #pragma unroll
                for (int ni = 0; ni < 4; ++ni) {
                    bf16x8 bf = *(const bf16x8*)&CB[(size_t)(ni * 16 + (l & 15)) * 64
                                                    + kb * 32 + (l >> 4) * 8];
                    acc[ni] = __builtin_amdgcn_mfma_f32_16x16x32_bf16(af, bf, acc[ni], 0, 0, 0);
                }
            }
        }
        #pragma unroll
        for (int ni = 0; ni < 4; ++ni)
            #pragma unroll
            for (int q = 0; q < 4; ++q)
                Sb[w * 16 + ((l >> 4) << 2) + q][ni * 16 + (l & 15)] = f2bf(acc[ni][q]);
        __syncthreads();
        f32x4 acc2[4] = {};
        #pragma unroll
        for (int kb = 0; kb < 2; ++kb) {
            bf16x8 af = *(const bf16x8*)&Sb[w * 16 + (l & 15)][kb * 32 + (l >> 4) * 8];
            #pragma unroll
            for (int ni = 0; ni < 4; ++ni) {
                const u16x8* dp = (const u16x8*)(Dmk + (size_t)I * 4096
                                  + (ni * 16 + (l & 15)) * 64 + kb * 32 + (l >> 4) * 8);
                u16x8 dv = *dp ^ (unsigned short)0x8000;  // negate bf16
                bf16x8 bf = __builtin_bit_cast(bf16x8, dv);
                acc2[ni] = __builtin_amdgcn_mfma_f32_16x16x32_bf16(af, bf, acc2[ni], 0, 0, 0);
            }
        }
        #pragma unroll
        for (int ni = 0; ni < 4; ++ni)
            #pragma unroll
            for (int q = 0; q < 4; ++q) {
                int c = w * 16 + ((l >> 4) << 2) + q;
                int r = ni * 16 + (l & 15);
                unsigned short hv = f2bf(acc2[ni][q]);
                Xp[I][c][r] = hv;
                Lout[(size_t)(I * 64 + r) * D_F + jc0 + c] = hv;
            }
        __syncthreads();
    }

    if (tid < 64) muS[tid] = means[(size_t)mk * D_F + jc0 + tid];
    __syncthreads();
    {
        int I = w, r = l;
        float s = 0.0f;
        if (I >= J) {
            for (int c = 0; c < 64; ++c)
                s += bf2f(Xp[I][c][r]) * muS[c];
        }
        cpart[((size_t)mk * 4 + J) * 256 + tid] = s;
    }
}

// ---------------- K4: extractor GEMM, BK=128 (halved barrier count) ------------
__global__ __launch_bounds__(256) void k_feat(const float* __restrict__ x,
                                              const unsigned short* __restrict__ wt,
                                              const float* __restrict__ bias,
                                              unsigned short* __restrict__ fb) {
    __shared__ unsigned short As[64][128];  // 16 KB
    __shared__ unsigned short Bs[64][128];  // 16 KB
    int b0 = blockIdx.x * 64;
    int n0 = blockIdx.y * 64;
    int tid = threadIdx.x, w = tid >> 6, l = tid & 63;
    int wm = w >> 1, wn = w & 1;
    f32x4 acc[2][2] = {};
    for (int k0 = 0; k0 < D_IN; k0 += 128) {
        float4_ av[4][2];
        #pragma unroll
        for (int it = 0; it < 4; ++it) {
            int o16 = tid + it * 256;
            int r = o16 >> 4, c = o16 & 15;
            const float* gp = x + (size_t)(b0 + r) * D_IN + k0 + c * 8;
            av[it][0] = *(const float4_*)gp;
            av[it][1] = *(const float4_*)(gp + 4);
        }
        __syncthreads();  // previous compute done reading LDS
        #pragma unroll
        for (int it = 0; it < 4; ++it) {
            int o16 = tid + it * 256;
            int r = o16 >> 4, c = o16 & 15;
            int cs = c ^ (r & 7);
            *(bf16x8*)&As[r][cs * 8] = pack8(av[it][0], av[it][1]);
            gload_lds16(wt + (size_t)(n0 + r) * D_IN + k0 + cs * 8, &Bs[0][0] + o16 * 8);
        }
        __syncthreads();  // staging complete
        #pragma unroll
        for (int ks = 0; ks < 4; ++ks) {
            int uw = ((ks * 4 + (l >> 4)) ^ (l & 7)) * 8;  // swizzled col
            bf16x8 af[2], bg[2];
            #pragma unroll
            for (int mi = 0; mi < 2; ++mi)
                af[mi] = *(const bf16x8*)&As[wm * 32 + mi * 16 + (l & 15)][uw];
            #pragma unroll
            for (int ni = 0; ni < 2; ++ni)
                bg[ni] = *(const bf16x8*)&Bs[wn * 32 + ni * 16 + (l & 15)][uw];
            #pragma unroll
            for (int mi = 0; mi < 2; ++mi)
                #pragma unroll
                for (int ni = 0; ni < 2; ++ni)
                    acc[mi][ni] = __builtin_amdgcn_mfma_f32_16x16x32_bf16(
                        af[mi], bg[ni], acc[mi][ni], 0, 0, 0);
        }
    }
    #pragma unroll
    for (int mi = 0; mi < 2; ++mi)
        #pragma unroll
        for (int ni = 0; ni < 2; ++ni) {
            int d = n0 + wn * 32 + ni * 16 + (l & 15);
            float bia = bias[d];
            #pragma unroll
            for (int r = 0; r < 4; ++r) {
                int b = b0 + wm * 32 + mi * 16 + (l >> 4) * 4 + r;
                float v = fmaxf(acc[mi][ni][r] + bia, 0.0f);
                fb[(size_t)b * D_F + d] = f2bf(v);
            }
        }
}

// ---------------- K7: big GEMM Z = Linv @ F^T, BN=256 (2-phase, 2 blocks/CU) ---
// BM=256, BN=256, BK=64. 512 threads = 8 waves (2M x 4N), wave tile 128x64.
// Same sync/swizzle structure as the R3-proven kernel; only the N-tile doubles
// -> 64 MFMAs per wave per K-step (was 32) against 1.5x staging volume.
__global__ __launch_bounds__(512) void k_gmm(const unsigned short* __restrict__ linv,
                                             const unsigned short* __restrict__ fb,
                                             const float* __restrict__ cpart,
                                             const float* __restrict__ wmix,
                                             const float* __restrict__ ldet,
                                             float* __restrict__ out) {
    __shared__ unsigned short As[256][64];  // 32 KB, swizzled 16B chunks
    __shared__ unsigned short Bs[256][64];  // 32 KB, swizzled
    __shared__ float cb[D_F];
    __shared__ float qpart[2][256];
    int mk = blockIdx.x;
    int b0 = blockIdx.y * 256;
    int tid = threadIdx.x, w = tid >> 6, l = tid & 63;
    int wm = w >> 2, wn = w & 3;
    const unsigned short* Ab = linv + (size_t)mk * D_F * D_F;
    if (tid < D_F) {
        const float* cp = cpart + (size_t)mk * 4 * D_F + tid;
        cb[tid] = cp[0] + cp[256] + cp[512] + cp[768];
    }
    f32x4 acc[8][4] = {};
    for (int k0 = 0; k0 < D_F; k0 += 64) {
        #pragma unroll
        for (int it = 0; it < 4; ++it) {
            int o16 = tid + it * 512;
            int r = o16 >> 3, c8 = (o16 & 7) ^ (r & 7);
            gload_lds16(Ab + (size_t)r * D_F + k0 + c8 * 8, &As[0][0] + o16 * 8);
        }
        #pragma unroll
        for (int it = 0; it < 4; ++it) {
            int o16 = tid + it * 512;
            int r = o16 >> 3, c8 = (o16 & 7) ^ (r & 7);
            gload_lds16(fb + (size_t)(b0 + r) * D_F + k0 + c8 * 8, &Bs[0][0] + o16 * 8);
        }
        __syncthreads();
        #pragma unroll
        for (int ks = 0; ks < 2; ++ks) {
            int uw = ((ks * 4 + (l >> 4)) ^ (l & 7)) * 8;  // swizzled col
            bf16x8 bg[4];
            #pragma unroll
            for (int ni = 0; ni < 4; ++ni)
                bg[ni] = *(const bf16x8*)&Bs[wn * 64 + ni * 16 + (l & 15)][uw];
            #pragma unroll
            for (int mi = 0; mi < 8; ++mi) {
                bf16x8 af = *(const bf16x8*)&As[wm * 128 + mi * 16 + (l & 15)][uw];
                #pragma unroll
                for (int ni = 0; ni < 4; ++ni)
                    acc[mi][ni] = __builtin_amdgcn_mfma_f32_16x16x32_bf16(
                        af, bg[ni], acc[mi][ni], 0, 0, 0);
            }
        }
        __syncthreads();
    }
    float p[4] = {0, 0, 0, 0};
    #pragma unroll
    for (int mi = 0; mi < 8; ++mi) {
        int ibase = wm * 128 + mi * 16 + ((l >> 4) << 2);
        #pragma unroll
        for (int r = 0; r < 4; ++r) {
            float cv = cb[ibase + r];
            #pragma unroll
            for (int ni = 0; ni < 4; ++ni) {
                float z = acc[mi][ni][r] - cv;
                p[ni] += z * z;
            }
        }
    }
    #pragma unroll
    for (int ni = 0; ni < 4; ++ni) {
        p[ni] += __shfl_xor(p[ni], 16);
        p[ni] += __shfl_xor(p[ni], 32);
    }
    if (l < 16) {
        #pragma unroll
        for (int ni = 0; ni < 4; ++ni)
            qpart[wm][wn * 64 + ni * 16 + l] = p[ni];
    }
    __syncthreads();
    if (tid < 256) {
        float q = qpart[0][tid] + qpart[1][tid];
        float lp = -0.5f * (q + (float)D_F * LOG2PI) - ldet[mk];
        out[(size_t)(b0 + tid) * MK + mk] = wmix[mk] * lp;
    }
}

extern "C" void kernel_launch(void* const* d_in, const int* in_sizes, int n_in,
                              void* d_out, int out_size, void* d_ws, size_t ws_size,
                              hipStream_t stream) {
    const float* x     = (const float*)d_in[0];
    const float* W     = (const float*)d_in[1];
    const float* bias  = (const float*)d_in[2];
    const float* means = (const float*)d_in[3];
    const float* covs  = (const float*)d_in[4];
    const float* wts   = (const float*)d_in[5];
    float* out = (float*)d_out;

    char* ws = (char*)d_ws;
    unsigned short* covsb = (unsigned short*)(ws);              // 6.55 MB [mk][10][4096]
    unsigned short* wt    = (unsigned short*)(ws + 6553600);    // 0.5 MB
    unsigned short* fb    = (unsigned short*)(ws + 7077888);    // 2 MB
    unsigned short* linv  = (unsigned short*)(ws + 9175040);    // 10.5 MB
    float* wmix = (float*)(ws + 19742720);                      // 320 B
    float* ldet = (float*)(ws + 19743040);                      // 320 B
    // cpart (320 KB) aliases wt: wt dead after k_feat, cpart written after.
    float* cpart = (float*)(ws + 6553600);

    k_pre<<<dim3(544), dim3(256), 0, stream>>>(W, covs, wts, wt, wmix, ldet, covsb);
    k_feat<<<dim3(64, 4), dim3(256), 0, stream>>>(x, wt, bias, fb);   // last use of wt
    k_inv_panel<<<dim3(MK, 4), dim3(256), 0, stream>>>(covsb, means, linv, cpart);
    k_gmm<<<dim3(MK, 16), dim3(512), 0, stream>>>(linv, fb, cpart, wmix, ldet, out);
}

// Round 14
// 80.921 us; speedup vs baseline: 1.1146x; 1.1146x over previous
//
#include <hip/hip_runtime.h>

#define B_N 4096
#define D_IN 1024
#define D_F 256
#define MK 80
#define LOG2PI 1.8378770664093453f
#define XP_S 72  // padded LDS row stride (bf16 elems)

typedef float f32x4 __attribute__((ext_vector_type(4)));
typedef short bf16x8 __attribute__((ext_vector_type(8)));
typedef float float4_ __attribute__((ext_vector_type(4)));
typedef unsigned int u32x4 __attribute__((ext_vector_type(4)));
typedef unsigned short u16x8 __attribute__((ext_vector_type(8)));

__device__ __forceinline__ unsigned short f2bf(float f) {
    unsigned u = __float_as_uint(f);
    u += 0x7fffu + ((u >> 16) & 1u);
    return (unsigned short)(u >> 16);
}
__device__ __forceinline__ float bf2f(unsigned short h) {
    return __uint_as_float(((unsigned)h) << 16);
}
__device__ __forceinline__ void gload_lds16(const void* g, void* l) {
    __builtin_amdgcn_global_load_lds((const __attribute__((address_space(1))) void*)g,
                                     (__attribute__((address_space(3))) void*)l, 16, 0, 0);
}
__device__ __forceinline__ bf16x8 pack8(float4_ a, float4_ b) {
    bf16x8 r;
    r[0] = (short)f2bf(a.x); r[1] = (short)f2bf(a.y);
    r[2] = (short)f2bf(a.z); r[3] = (short)f2bf(a.w);
    r[4] = (short)f2bf(b.x); r[5] = (short)f2bf(b.y);
    r[6] = (short)f2bf(b.z); r[7] = (short)f2bf(b.w);
    return r;
}

// ---------------- K_pre: W-transpose, stats, covs->bf16, diag-block Neumann ----
// grid 544: [0,64) W-transpose, [64,144) stats, [144,224) off-diag covsb (plain
// bf16 L blocks), [224,544) diag-block inversion (mk,I) via Neumann + MFMA.
// covsb per mk: [0..5] off-diag L(I,K) K<I at idx I*(I-1)/2+K; [6..9] Dinv.
__global__ __launch_bounds__(256) void k_pre(const float* __restrict__ W,
                                             const float* __restrict__ covs,
                                             const float* __restrict__ wts,
                                             unsigned short* __restrict__ wt,
                                             float* __restrict__ wmix,
                                             float* __restrict__ ldet,
                                             unsigned short* __restrict__ covsb) {
    int bx = blockIdx.x, tid = threadIdx.x;
    if (bx < 64) {
        __shared__ unsigned short t[64][65];
        int k0 = (bx >> 2) * 64, n0 = (bx & 3) * 64;
        int r = tid / 64, c = tid % 64;
        #pragma unroll
        for (int rr = r; rr < 64; rr += 4)
            t[rr][c] = f2bf(W[(size_t)(k0 + rr) * D_F + n0 + c]);
        __syncthreads();
        #pragma unroll
        for (int rr = r; rr < 64; rr += 4)
            wt[(size_t)(n0 + rr) * D_IN + k0 + c] = t[c][rr];
    } else if (bx < 144) {
        if (tid < 64) {
            int mk = bx - 64;
            int l = tid;
            const float* Lm = covs + (size_t)mk * D_F * D_F;
            float s = 0.0f;
            for (int i = l; i < D_F; i += 64) s += logf(Lm[(size_t)i * D_F + i]);
            for (int off = 32; off; off >>= 1) s += __shfl_down(s, off);
            if (l == 0) {
                ldet[mk] = s;
                int m = mk / 8, k = mk % 8;
                float mx = -1e30f;
                for (int j = 0; j < 8; j++) mx = fmaxf(mx, wts[m * 8 + j]);
                float sum = 0.0f;
                for (int j = 0; j < 8; j++) sum += expf(wts[m * 8 + j] - mx);
                wmix[mk] = expf(wts[m * 8 + k] - mx) / sum;
            }
        }
    } else if (bx < 224) {
        // covs off-diag lower blocks -> plain bf16: (I,K), K<I, idx = I*(I-1)/2+K
        int mk = bx - 144;
        const float* Cm = covs + (size_t)mk * D_F * D_F;
        unsigned short* Cb = covsb + (size_t)mk * 10 * 4096;
        #pragma unroll
        for (int I = 1; I < 4; ++I)
            for (int K = 0; K < I; ++K) {
                int idx = (I * (I - 1)) / 2 + K;
                for (int t4 = tid; t4 < 1024; t4 += 256) {
                    int r = t4 >> 4, kq = t4 & 15;
                    float4_ v = *(const float4_*)&Cm[(size_t)(I * 64 + r) * D_F
                                                     + K * 64 + kq * 4];
                    ushort4 o;
                    o.x = f2bf(v.x); o.y = f2bf(v.y); o.z = f2bf(v.z); o.w = f2bf(v.w);
                    *(ushort4*)&Cb[(size_t)idx * 4096 + r * 64 + kq * 4] = o;
                }
            }
    } else {
        // diag-block inverse via Neumann: Dinv = (I - X + X^2 - X^3 + X^4) D^-1,
        // X = D^-1 strict_lower(Ldiag), ||X|| ~ 0.08 -> truncation ~3e-6.
        int b = bx - 224;
        int mk = b >> 2, I = b & 3;
        int i0 = I * 64;
        __shared__ float rl[64];
        __shared__ unsigned short X[64][XP_S];
        __shared__ unsigned short Yt[2][64][XP_S];
        int w = tid >> 6, l = tid & 63;
        const float* Cm = covs + (size_t)mk * D_F * D_F;
        if (tid < 64) rl[tid] = 1.0f / Cm[(size_t)(i0 + tid) * D_F + i0 + tid];
        __syncthreads();
        // build X (row-scaled strict lower) directly in LDS
        for (int t4 = tid; t4 < 1024; t4 += 256) {
            int r = t4 >> 4, kq = t4 & 15;
            float4_ v = *(const float4_*)&Cm[(size_t)(i0 + r) * D_F + i0 + kq * 4];
            float ri = rl[r];
            int base = kq * 4;
            ushort4 o;
            o.x = (base     < r) ? f2bf(v.x * ri) : (unsigned short)0;
            o.y = (base + 1 < r) ? f2bf(v.y * ri) : (unsigned short)0;
            o.z = (base + 2 < r) ? f2bf(v.z * ri) : (unsigned short)0;
            o.w = (base + 3 < r) ? f2bf(v.w * ri) : (unsigned short)0;
            *(ushort4*)&X[r][base] = o;
        }
        __syncthreads();
        // T1 = I - X (transposed): Yt[0][j][i] = delta_ij - X[i][j]
        for (int t = tid; t < 4096; t += 256) {
            int j = t >> 6, i = t & 63;
            unsigned short xv = X[i][j];
            Yt[0][j][i] = (i == j) ? (unsigned short)0x3F80
                                   : (unsigned short)(xv ^ 0x8000u);
        }
        __syncthreads();
        int cur = 0;
        for (int it = 0; it < 3; ++it) {
            bf16x8 a0 = *(const bf16x8*)&Yt[cur][16 * w + (l & 15)][(l >> 4) * 8];
            bf16x8 a1 = *(const bf16x8*)&Yt[cur][16 * w + (l & 15)][32 + (l >> 4) * 8];
            f32x4 acc[4] = {{0, 0, 0, 0}, {0, 0, 0, 0}, {0, 0, 0, 0}, {0, 0, 0, 0}};
            #pragma unroll
            for (int ni = 0; ni < 4; ++ni) {
                bf16x8 b0 = *(const bf16x8*)&X[ni * 16 + (l & 15)][(l >> 4) * 8];
                bf16x8 b1 = *(const bf16x8*)&X[ni * 16 + (l & 15)][32 + (l >> 4) * 8];
                acc[ni] = __builtin_amdgcn_mfma_f32_16x16x32_bf16(a0, b0, acc[ni], 0, 0, 0);
                acc[ni] = __builtin_amdgcn_mfma_f32_16x16x32_bf16(a1, b1, acc[ni], 0, 0, 0);
            }
            #pragma unroll
            for (int ni = 0; ni < 4; ++ni)
                #pragma unroll
                for (int q = 0; q < 4; ++q) {
                    int i = ni * 16 + (l & 15);
                    int j = 16 * w + (l >> 4) * 4 + q;
                    float v = ((i == j) ? 1.0f : 0.0f) - acc[ni][q];
                    Yt[cur ^ 1][j][i] = f2bf(v);
                }
            __syncthreads();
            cur ^= 1;
        }
        // Dinv[r][c] = Yt[cur][c][r] * rl[c] -> covsb slot [6+I]
        unsigned short* Xg = covsb + ((size_t)mk * 10 + 6 + I) * 4096;
        for (int t = tid; t < 4096; t += 256) {
            int r = t >> 6, c = t & 63;
            Xg[t] = f2bf(bf2f(Yt[cur][c][r]) * rl[c]);
        }
    }
}

// ---------------- K5b: column panels of Linv via blocked MFMA + cvec partial ---
__global__ __launch_bounds__(256) void k_inv_panel(
        const unsigned short* __restrict__ covsb,
        const float* __restrict__ means,
        unsigned short* __restrict__ linv,
        float* __restrict__ cpart) {
    int mk = blockIdx.x, J = blockIdx.y;
    int jc0 = J * 64;
    __shared__ unsigned short Xp[4][64][XP_S];  // 73.7 KB
    __shared__ unsigned short Sb[64][XP_S];     // 9.2 KB
    __shared__ float muS[64];
    int tid = threadIdx.x, w = tid >> 6, l = tid & 63;
    const unsigned short* Cb = covsb + (size_t)mk * 10 * 4096;   // off-diag [0..5]
    const unsigned short* Dmk = Cb + 6 * 4096;                   // Dinv [6..9]
    unsigned short* Lout = linv + (size_t)mk * D_F * D_F;

    for (int t = tid; t < jc0 * 8; t += 256) {
        int r = t >> 3, s = t & 7;
        ((u32x4*)(Lout + (size_t)r * D_F + jc0))[s] = (u32x4){0, 0, 0, 0};
    }
    const unsigned short* DJ = Dmk + J * 4096;
    for (int t = tid; t < 4096; t += 256) {
        int r = t >> 6, c = t & 63;
        Xp[J][c][r] = DJ[t];
    }
    for (int t = tid; t < 512; t += 256) {
        int r = t >> 3, s = t & 7;
        ((u32x4*)(Lout + (size_t)(jc0 + r) * D_F + jc0))[s] = ((const u32x4*)(DJ + r * 64))[s];
    }
    __syncthreads();

    for (int I = J + 1; I < 4; ++I) {
        f32x4 acc[4] = {};
        for (int K = J; K < I; ++K) {
            const unsigned short* CB = Cb + (size_t)((I * (I - 1)) / 2 + K) * 4096;
            #pragma unroll
            for (int kb = 0; kb < 2; ++kb) {
                bf16x8 af = *(const bf16x8*)&Xp[K][w * 16 + (l & 15)][kb * 32 + (l >> 4) * 8];
                #pragma unroll
                for (int ni = 0; ni < 4; ++ni) {
                    bf16x8 bf = *(const bf16x8*)&CB[(size_t)(ni * 16 + (l & 15)) * 64
                                                    + kb * 32 + (l >> 4) * 8];
                    acc[ni] = __builtin_amdgcn_mfma_f32_16x16x32_bf16(af, bf, acc[ni], 0, 0, 0);
                }
            }
        }
        #pragma unroll
        for (int ni = 0; ni < 4; ++ni)
            #pragma unroll
            for (int q = 0; q < 4; ++q)
                Sb[w * 16 + ((l >> 4) << 2) + q][ni * 16 + (l & 15)] = f2bf(acc[ni][q]);
        __syncthreads();
        f32x4 acc2[4] = {};
        #pragma unroll
        for (int kb = 0; kb < 2; ++kb) {
            bf16x8 af = *(const bf16x8*)&Sb[w * 16 + (l & 15)][kb * 32 + (l >> 4) * 8];
            #pragma unroll
            for (int ni = 0; ni < 4; ++ni) {
                const u16x8* dp = (const u16x8*)(Dmk + (size_t)I * 4096
                                  + (ni * 16 + (l & 15)) * 64 + kb * 32 + (l >> 4) * 8);
                u16x8 dv = *dp ^ (unsigned short)0x8000;  // negate bf16
                bf16x8 bf = __builtin_bit_cast(bf16x8, dv);
                acc2[ni] = __builtin_amdgcn_mfma_f32_16x16x32_bf16(af, bf, acc2[ni], 0, 0, 0);
            }
        }
        #pragma unroll
        for (int ni = 0; ni < 4; ++ni)
            #pragma unroll
            for (int q = 0; q < 4; ++q) {
                int c = w * 16 + ((l >> 4) << 2) + q;
                int r = ni * 16 + (l & 15);
                unsigned short hv = f2bf(acc2[ni][q]);
                Xp[I][c][r] = hv;
                Lout[(size_t)(I * 64 + r) * D_F + jc0 + c] = hv;
            }
        __syncthreads();
    }

    if (tid < 64) muS[tid] = means[(size_t)mk * D_F + jc0 + tid];
    __syncthreads();
    {
        int I = w, r = l;
        float s = 0.0f;
        if (I >= J) {
            for (int c = 0; c < 64; ++c)
                s += bf2f(Xp[I][c][r]) * muS[c];
        }
        cpart[((size_t)mk * 4 + J) * 256 + tid] = s;
    }
}

// ---------------- K4: extractor GEMM, BK=128 (halved barrier count) ------------
__global__ __launch_bounds__(256) void k_feat(const float* __restrict__ x,
                                              const unsigned short* __restrict__ wt,
                                              const float* __restrict__ bias,
                                              unsigned short* __restrict__ fb) {
    __shared__ unsigned short As[64][128];  // 16 KB
    __shared__ unsigned short Bs[64][128];  // 16 KB
    int b0 = blockIdx.x * 64;
    int n0 = blockIdx.y * 64;
    int tid = threadIdx.x, w = tid >> 6, l = tid & 63;
    int wm = w >> 1, wn = w & 1;
    f32x4 acc[2][2] = {};
    for (int k0 = 0; k0 < D_IN; k0 += 128) {
        float4_ av[4][2];
        #pragma unroll
        for (int it = 0; it < 4; ++it) {
            int o16 = tid + it * 256;
            int r = o16 >> 4, c = o16 & 15;
            const float* gp = x + (size_t)(b0 + r) * D_IN + k0 + c * 8;
            av[it][0] = *(const float4_*)gp;
            av[it][1] = *(const float4_*)(gp + 4);
        }
        __syncthreads();  // previous compute done reading LDS
        #pragma unroll
        for (int it = 0; it < 4; ++it) {
            int o16 = tid + it * 256;
            int r = o16 >> 4, c = o16 & 15;
            int cs = c ^ (r & 7);
            *(bf16x8*)&As[r][cs * 8] = pack8(av[it][0], av[it][1]);
            gload_lds16(wt + (size_t)(n0 + r) * D_IN + k0 + cs * 8, &Bs[0][0] + o16 * 8);
        }
        __syncthreads();  // staging complete
        #pragma unroll
        for (int ks = 0; ks < 4; ++ks) {
            int uw = ((ks * 4 + (l >> 4)) ^ (l & 7)) * 8;  // swizzled col
            bf16x8 af[2], bg[2];
            #pragma unroll
            for (int mi = 0; mi < 2; ++mi)
                af[mi] = *(const bf16x8*)&As[wm * 32 + mi * 16 + (l & 15)][uw];
            #pragma unroll
            for (int ni = 0; ni < 2; ++ni)
                bg[ni] = *(const bf16x8*)&Bs[wn * 32 + ni * 16 + (l & 15)][uw];
            #pragma unroll
            for (int mi = 0; mi < 2; ++mi)
                #pragma unroll
                for (int ni = 0; ni < 2; ++ni)
                    acc[mi][ni] = __builtin_amdgcn_mfma_f32_16x16x32_bf16(
                        af[mi], bg[ni], acc[mi][ni], 0, 0, 0);
        }
    }
    #pragma unroll
    for (int mi = 0; mi < 2; ++mi)
        #pragma unroll
        for (int ni = 0; ni < 2; ++ni) {
            int d = n0 + wn * 32 + ni * 16 + (l & 15);
            float bia = bias[d];
            #pragma unroll
            for (int r = 0; r < 4; ++r) {
                int b = b0 + wm * 32 + mi * 16 + (l >> 4) * 4 + r;
                float v = fmaxf(acc[mi][ni][r] + bia, 0.0f);
                fb[(size_t)b * D_F + d] = f2bf(v);
            }
        }
}

// ---------------- K7: big GEMM Z = Linv @ F^T (R3 structure + triangular skip) -
// A = Linv is lower-triangular: A[m][k] == 0 exactly for k > m (upper panels
// memset; Dinv upper exact zeros by Neumann induction). Fragment groups with
// k0+ks*32 > row_hi multiply an all-zero A fragment -> skipped (44% of A-side
// MFMAs + their af ds_reads), wave-uniform branch, exact arithmetic.
__global__ __launch_bounds__(512) void k_gmm(const unsigned short* __restrict__ linv,
                                             const unsigned short* __restrict__ fb,
                                             const float* __restrict__ cpart,
                                             const float* __restrict__ wmix,
                                             const float* __restrict__ ldet,
                                             float* __restrict__ out) {
    __shared__ unsigned short As[256][64];  // 32 KB, swizzled 16B chunks
    __shared__ unsigned short Bs[128][64];  // 16 KB, swizzled
    __shared__ float cb[D_F];
    __shared__ float qpart[4][128];
    int mk = blockIdx.x;
    int b0 = blockIdx.y * 128;
    int tid = threadIdx.x, w = tid >> 6, l = tid & 63;
    int wm = w >> 1, wn = w & 1;
    const unsigned short* Ab = linv + (size_t)mk * D_F * D_F;
    if (tid < D_F) {
        const float* cp = cpart + (size_t)mk * 4 * D_F + tid;
        cb[tid] = cp[0] + cp[256] + cp[512] + cp[768];
    }
    f32x4 acc[4][4] = {};
    for (int k0 = 0; k0 < D_F; k0 += 64) {
        #pragma unroll
        for (int it = 0; it < 4; ++it) {
            int o16 = tid + it * 512;
            int r = o16 >> 3, c8 = (o16 & 7) ^ (r & 7);
            gload_lds16(Ab + (size_t)r * D_F + k0 + c8 * 8, &As[0][0] + o16 * 8);
        }
        #pragma unroll
        for (int it = 0; it < 2; ++it) {
            int o16 = tid + it * 512;
            int r = o16 >> 3, c8 = (o16 & 7) ^ (r & 7);
            gload_lds16(fb + (size_t)(b0 + r) * D_F + k0 + c8 * 8, &Bs[0][0] + o16 * 8);
        }
        __syncthreads();
        #pragma unroll
        for (int ks = 0; ks < 2; ++ks) {
            int uw = ((ks * 4 + (l >> 4)) ^ (l & 7)) * 8;  // swizzled col
            bf16x8 bg[4];
            #pragma unroll
            for (int ni = 0; ni < 4; ++ni)
                bg[ni] = *(const bf16x8*)&Bs[wn * 64 + ni * 16 + (l & 15)][uw];
            #pragma unroll
            for (int mi = 0; mi < 4; ++mi) {
                // triangular skip: A rows [wm*64+mi*16, +16) are all-zero over
                // k in [k0+ks*32, +32) when the k-range lies above the diagonal
                if (k0 + ks * 32 <= wm * 64 + mi * 16 + 15) {
                    bf16x8 af = *(const bf16x8*)&As[wm * 64 + mi * 16 + (l & 15)][uw];
                    #pragma unroll
                    for (int ni = 0; ni < 4; ++ni)
                        acc[mi][ni] = __builtin_amdgcn_mfma_f32_16x16x32_bf16(
                            af, bg[ni], acc[mi][ni], 0, 0, 0);
                }
            }
        }
        __syncthreads();
    }
    float p[4] = {0, 0, 0, 0};
    #pragma unroll
    for (int mi = 0; mi < 4; ++mi) {
        int ibase = wm * 64 + mi * 16 + ((l >> 4) << 2);
        #pragma unroll
        for (int r = 0; r < 4; ++r) {
            float cv = cb[ibase + r];
            #pragma unroll
            for (int ni = 0; ni < 4; ++ni) {
                float z = acc[mi][ni][r] - cv;
                p[ni] += z * z;
            }
        }
    }
    #pragma unroll
    for (int ni = 0; ni < 4; ++ni) {
        p[ni] += __shfl_xor(p[ni], 16);
        p[ni] += __shfl_xor(p[ni], 32);
    }
    if (l < 16) {
        #pragma unroll
        for (int ni = 0; ni < 4; ++ni)
            qpart[wm][wn * 64 + ni * 16 + l] = p[ni];
    }
    __syncthreads();
    if (tid < 128) {
        float q = qpart[0][tid] + qpart[1][tid] + qpart[2][tid] + qpart[3][tid];
        float lp = -0.5f * (q + (float)D_F * LOG2PI) - ldet[mk];
        out[(size_t)(b0 + tid) * MK + mk] = wmix[mk] * lp;
    }
}

extern "C" void kernel_launch(void* const* d_in, const int* in_sizes, int n_in,
                              void* d_out, int out_size, void* d_ws, size_t ws_size,
                              hipStream_t stream) {
    const float* x     = (const float*)d_in[0];
    const float* W     = (const float*)d_in[1];
    const float* bias  = (const float*)d_in[2];
    const float* means = (const float*)d_in[3];
    const float* covs  = (const float*)d_in[4];
    const float* wts   = (const float*)d_in[5];
    float* out = (float*)d_out;

    char* ws = (char*)d_ws;
    unsigned short* covsb = (unsigned short*)(ws);              // 6.55 MB [mk][10][4096]
    unsigned short* wt    = (unsigned short*)(ws + 6553600);    // 0.5 MB
    unsigned short* fb    = (unsigned short*)(ws + 7077888);    // 2 MB
    unsigned short* linv  = (unsigned short*)(ws + 9175040);    // 10.5 MB
    float* wmix = (float*)(ws + 19742720);                      // 320 B
    float* ldet = (float*)(ws + 19743040);                      // 320 B
    // cpart (320 KB) aliases wt: wt dead after k_feat, cpart written after.
    float* cpart = (float*)(ws + 6553600);

    k_pre<<<dim3(544), dim3(256), 0, stream>>>(W, covs, wts, wt, wmix, ldet, covsb);
    k_feat<<<dim3(64, 4), dim3(256), 0, stream>>>(x, wt, bias, fb);   // last use of wt
    k_inv_panel<<<dim3(MK, 4), dim3(256), 0, stream>>>(covsb, means, linv, cpart);
    k_gmm<<<dim3(MK, 32), dim3(512), 0, stream>>>(linv, fb, cpart, wmix, ldet, out);
}

// Round 15
// 78.714 us; speedup vs baseline: 1.1459x; 1.0280x over previous
//
#include <hip/hip_runtime.h>

#define B_N 4096
#define D_IN 1024
#define D_F 256
#define MK 80
#define LOG2PI 1.8378770664093453f
#define XP_S 72  // padded LDS row stride (bf16 elems)

typedef float f32x4 __attribute__((ext_vector_type(4)));
typedef short bf16x8 __attribute__((ext_vector_type(8)));
typedef float float4_ __attribute__((ext_vector_type(4)));
typedef unsigned int u32x4 __attribute__((ext_vector_type(4)));
typedef unsigned short u16x8 __attribute__((ext_vector_type(8)));

__device__ __forceinline__ unsigned short f2bf(float f) {
    unsigned u = __float_as_uint(f);
    u += 0x7fffu + ((u >> 16) & 1u);
    return (unsigned short)(u >> 16);
}
__device__ __forceinline__ float bf2f(unsigned short h) {
    return __uint_as_float(((unsigned)h) << 16);
}
__device__ __forceinline__ void gload_lds16(const void* g, void* l) {
    __builtin_amdgcn_global_load_lds((const __attribute__((address_space(1))) void*)g,
                                     (__attribute__((address_space(3))) void*)l, 16, 0, 0);
}
__device__ __forceinline__ bf16x8 pack8(float4_ a, float4_ b) {
    bf16x8 r;
    r[0] = (short)f2bf(a.x); r[1] = (short)f2bf(a.y);
    r[2] = (short)f2bf(a.z); r[3] = (short)f2bf(a.w);
    r[4] = (short)f2bf(b.x); r[5] = (short)f2bf(b.y);
    r[6] = (short)f2bf(b.z); r[7] = (short)f2bf(b.w);
    return r;
}

// ---------------- K_pre: W-transpose, stats, covs->bf16, diag-block Neumann ----
// grid 544: [0,64) W-transpose, [64,144) stats, [144,224) off-diag covsb (plain
// bf16 L blocks), [224,544) diag-block inversion (mk,I) via Neumann + MFMA.
// covsb per mk: [0..5] off-diag L(I,K) K<I at idx I*(I-1)/2+K; [6..9] Dinv.
__global__ __launch_bounds__(256) void k_pre(const float* __restrict__ W,
                                             const float* __restrict__ covs,
                                             const float* __restrict__ wts,
                                             unsigned short* __restrict__ wt,
                                             float* __restrict__ wmix,
                                             float* __restrict__ ldet,
                                             unsigned short* __restrict__ covsb) {
    int bx = blockIdx.x, tid = threadIdx.x;
    if (bx < 64) {
        __shared__ unsigned short t[64][65];
        int k0 = (bx >> 2) * 64, n0 = (bx & 3) * 64;
        int r = tid / 64, c = tid % 64;
        #pragma unroll
        for (int rr = r; rr < 64; rr += 4)
            t[rr][c] = f2bf(W[(size_t)(k0 + rr) * D_F + n0 + c]);
        __syncthreads();
        #pragma unroll
        for (int rr = r; rr < 64; rr += 4)
            wt[(size_t)(n0 + rr) * D_IN + k0 + c] = t[c][rr];
    } else if (bx < 144) {
        if (tid < 64) {
            int mk = bx - 64;
            int l = tid;
            const float* Lm = covs + (size_t)mk * D_F * D_F;
            float s = 0.0f;
            for (int i = l; i < D_F; i += 64) s += logf(Lm[(size_t)i * D_F + i]);
            for (int off = 32; off; off >>= 1) s += __shfl_down(s, off);
            if (l == 0) {
                ldet[mk] = s;
                int m = mk / 8, k = mk % 8;
                float mx = -1e30f;
                for (int j = 0; j < 8; j++) mx = fmaxf(mx, wts[m * 8 + j]);
                float sum = 0.0f;
                for (int j = 0; j < 8; j++) sum += expf(wts[m * 8 + j] - mx);
                wmix[mk] = expf(wts[m * 8 + k] - mx) / sum;
            }
        }
    } else if (bx < 224) {
        // covs off-diag lower blocks -> plain bf16: (I,K), K<I, idx = I*(I-1)/2+K
        int mk = bx - 144;
        const float* Cm = covs + (size_t)mk * D_F * D_F;
        unsigned short* Cb = covsb + (size_t)mk * 10 * 4096;
        #pragma unroll
        for (int I = 1; I < 4; ++I)
            for (int K = 0; K < I; ++K) {
                int idx = (I * (I - 1)) / 2 + K;
                for (int t4 = tid; t4 < 1024; t4 += 256) {
                    int r = t4 >> 4, kq = t4 & 15;
                    float4_ v = *(const float4_*)&Cm[(size_t)(I * 64 + r) * D_F
                                                     + K * 64 + kq * 4];
                    ushort4 o;
                    o.x = f2bf(v.x); o.y = f2bf(v.y); o.z = f2bf(v.z); o.w = f2bf(v.w);
                    *(ushort4*)&Cb[(size_t)idx * 4096 + r * 64 + kq * 4] = o;
                }
            }
    } else {
        // diag-block inverse via Neumann: Dinv = (I - X + X^2 - X^3 + X^4) D^-1,
        // X = D^-1 strict_lower(Ldiag), ||X|| ~ 0.08 -> truncation ~3e-6.
        int b = bx - 224;
        int mk = b >> 2, I = b & 3;
        int i0 = I * 64;
        __shared__ float rl[64];
        __shared__ unsigned short X[64][XP_S];
        __shared__ unsigned short Yt[2][64][XP_S];
        int w = tid >> 6, l = tid & 63;
        const float* Cm = covs + (size_t)mk * D_F * D_F;
        if (tid < 64) rl[tid] = 1.0f / Cm[(size_t)(i0 + tid) * D_F + i0 + tid];
        __syncthreads();
        // build X (row-scaled strict lower) directly in LDS
        for (int t4 = tid; t4 < 1024; t4 += 256) {
            int r = t4 >> 4, kq = t4 & 15;
            float4_ v = *(const float4_*)&Cm[(size_t)(i0 + r) * D_F + i0 + kq * 4];
            float ri = rl[r];
            int base = kq * 4;
            ushort4 o;
            o.x = (base     < r) ? f2bf(v.x * ri) : (unsigned short)0;
            o.y = (base + 1 < r) ? f2bf(v.y * ri) : (unsigned short)0;
            o.z = (base + 2 < r) ? f2bf(v.z * ri) : (unsigned short)0;
            o.w = (base + 3 < r) ? f2bf(v.w * ri) : (unsigned short)0;
            *(ushort4*)&X[r][base] = o;
        }
        __syncthreads();
        // T1 = I - X (transposed): Yt[0][j][i] = delta_ij - X[i][j]
        for (int t = tid; t < 4096; t += 256) {
            int j = t >> 6, i = t & 63;
            unsigned short xv = X[i][j];
            Yt[0][j][i] = (i == j) ? (unsigned short)0x3F80
                                   : (unsigned short)(xv ^ 0x8000u);
        }
        __syncthreads();
        int cur = 0;
        for (int it = 0; it < 3; ++it) {
            bf16x8 a0 = *(const bf16x8*)&Yt[cur][16 * w + (l & 15)][(l >> 4) * 8];
            bf16x8 a1 = *(const bf16x8*)&Yt[cur][16 * w + (l & 15)][32 + (l >> 4) * 8];
            f32x4 acc[4] = {{0, 0, 0, 0}, {0, 0, 0, 0}, {0, 0, 0, 0}, {0, 0, 0, 0}};
            #pragma unroll
            for (int ni = 0; ni < 4; ++ni) {
                bf16x8 b0 = *(const bf16x8*)&X[ni * 16 + (l & 15)][(l >> 4) * 8];
                bf16x8 b1 = *(const bf16x8*)&X[ni * 16 + (l & 15)][32 + (l >> 4) * 8];
                acc[ni] = __builtin_amdgcn_mfma_f32_16x16x32_bf16(a0, b0, acc[ni], 0, 0, 0);
                acc[ni] = __builtin_amdgcn_mfma_f32_16x16x32_bf16(a1, b1, acc[ni], 0, 0, 0);
            }
            #pragma unroll
            for (int ni = 0; ni < 4; ++ni)
                #pragma unroll
                for (int q = 0; q < 4; ++q) {
                    int i = ni * 16 + (l & 15);
                    int j = 16 * w + (l >> 4) * 4 + q;
                    float v = ((i == j) ? 1.0f : 0.0f) - acc[ni][q];
                    Yt[cur ^ 1][j][i] = f2bf(v);
                }
            __syncthreads();
            cur ^= 1;
        }
        // Dinv[r][c] = Yt[cur][c][r] * rl[c] -> covsb slot [6+I]
        unsigned short* Xg = covsb + ((size_t)mk * 10 + 6 + I) * 4096;
        for (int t = tid; t < 4096; t += 256) {
            int r = t >> 6, c = t & 63;
            Xg[t] = f2bf(bf2f(Yt[cur][c][r]) * rl[c]);
        }
    }
}

// ---------------- K5b: column panels of Linv via blocked MFMA + cvec partial ---
// NOTE: upper-triangle of Lout is NEVER written (k_gmm's staging skip means it
// is never read either) -- the zeroing pass was removed.
__global__ __launch_bounds__(256) void k_inv_panel(
        const unsigned short* __restrict__ covsb,
        const float* __restrict__ means,
        unsigned short* __restrict__ linv,
        float* __restrict__ cpart) {
    int mk = blockIdx.x, J = blockIdx.y;
    int jc0 = J * 64;
    __shared__ unsigned short Xp[4][64][XP_S];  // 73.7 KB
    __shared__ unsigned short Sb[64][XP_S];     // 9.2 KB
    __shared__ float muS[64];
    int tid = threadIdx.x, w = tid >> 6, l = tid & 63;
    const unsigned short* Cb = covsb + (size_t)mk * 10 * 4096;   // off-diag [0..5]
    const unsigned short* Dmk = Cb + 6 * 4096;                   // Dinv [6..9]
    unsigned short* Lout = linv + (size_t)mk * D_F * D_F;

    const unsigned short* DJ = Dmk + J * 4096;
    for (int t = tid; t < 4096; t += 256) {
        int r = t >> 6, c = t & 63;
        Xp[J][c][r] = DJ[t];
    }
    for (int t = tid; t < 512; t += 256) {
        int r = t >> 3, s = t & 7;
        ((u32x4*)(Lout + (size_t)(jc0 + r) * D_F + jc0))[s] = ((const u32x4*)(DJ + r * 64))[s];
    }
    __syncthreads();

    for (int I = J + 1; I < 4; ++I) {
        f32x4 acc[4] = {};
        for (int K = J; K < I; ++K) {
            const unsigned short* CB = Cb + (size_t)((I * (I - 1)) / 2 + K) * 4096;
            #pragma unroll
            for (int kb = 0; kb < 2; ++kb) {
                bf16x8 af = *(const bf16x8*)&Xp[K][w * 16 + (l & 15)][kb * 32 + (l >> 4) * 8];
                #pragma unroll
                for (int ni = 0; ni < 4; ++ni) {
                    bf16x8 bf = *(const bf16x8*)&CB[(size_t)(ni * 16 + (l & 15)) * 64
                                                    + kb * 32 + (l >> 4) * 8];
                    acc[ni] = __builtin_amdgcn_mfma_f32_16x16x32_bf16(af, bf, acc[ni], 0, 0, 0);
                }
            }
        }
        #pragma unroll
        for (int ni = 0; ni < 4; ++ni)
            #pragma unroll
            for (int q = 0; q < 4; ++q)
                Sb[w * 16 + ((l >> 4) << 2) + q][ni * 16 + (l & 15)] = f2bf(acc[ni][q]);
        __syncthreads();
        f32x4 acc2[4] = {};
        #pragma unroll
        for (int kb = 0; kb < 2; ++kb) {
            bf16x8 af = *(const bf16x8*)&Sb[w * 16 + (l & 15)][kb * 32 + (l >> 4) * 8];
            #pragma unroll
            for (int ni = 0; ni < 4; ++ni) {
                const u16x8* dp = (const u16x8*)(Dmk + (size_t)I * 4096
                                  + (ni * 16 + (l & 15)) * 64 + kb * 32 + (l >> 4) * 8);
                u16x8 dv = *dp ^ (unsigned short)0x8000;  // negate bf16
                bf16x8 bf = __builtin_bit_cast(bf16x8, dv);
                acc2[ni] = __builtin_amdgcn_mfma_f32_16x16x32_bf16(af, bf, acc2[ni], 0, 0, 0);
            }
        }
        #pragma unroll
        for (int ni = 0; ni < 4; ++ni)
            #pragma unroll
            for (int q = 0; q < 4; ++q) {
                int c = w * 16 + ((l >> 4) << 2) + q;
                int r = ni * 16 + (l & 15);
                unsigned short hv = f2bf(acc2[ni][q]);
                Xp[I][c][r] = hv;
                Lout[(size_t)(I * 64 + r) * D_F + jc0 + c] = hv;
            }
        __syncthreads();
    }

    if (tid < 64) muS[tid] = means[(size_t)mk * D_F + jc0 + tid];
    __syncthreads();
    {
        int I = w, r = l;
        float s = 0.0f;
        if (I >= J) {
            for (int c = 0; c < 64; ++c)
                s += bf2f(Xp[I][c][r]) * muS[c];
        }
        cpart[((size_t)mk * 4 + J) * 256 + tid] = s;
    }
}

// ---------------- K4: extractor GEMM, BK=128 (halved barrier count) ------------
__global__ __launch_bounds__(256) void k_feat(const float* __restrict__ x,
                                              const unsigned short* __restrict__ wt,
                                              const float* __restrict__ bias,
                                              unsigned short* __restrict__ fb) {
    __shared__ unsigned short As[64][128];  // 16 KB
    __shared__ unsigned short Bs[64][128];  // 16 KB
    int b0 = blockIdx.x * 64;
    int n0 = blockIdx.y * 64;
    int tid = threadIdx.x, w = tid >> 6, l = tid & 63;
    int wm = w >> 1, wn = w & 1;
    f32x4 acc[2][2] = {};
    for (int k0 = 0; k0 < D_IN; k0 += 128) {
        float4_ av[4][2];
        #pragma unroll
        for (int it = 0; it < 4; ++it) {
            int o16 = tid + it * 256;
            int r = o16 >> 4, c = o16 & 15;
            const float* gp = x + (size_t)(b0 + r) * D_IN + k0 + c * 8;
            av[it][0] = *(const float4_*)gp;
            av[it][1] = *(const float4_*)(gp + 4);
        }
        __syncthreads();  // previous compute done reading LDS
        #pragma unroll
        for (int it = 0; it < 4; ++it) {
            int o16 = tid + it * 256;
            int r = o16 >> 4, c = o16 & 15;
            int cs = c ^ (r & 7);
            *(bf16x8*)&As[r][cs * 8] = pack8(av[it][0], av[it][1]);
            gload_lds16(wt + (size_t)(n0 + r) * D_IN + k0 + cs * 8, &Bs[0][0] + o16 * 8);
        }
        __syncthreads();  // staging complete
        #pragma unroll
        for (int ks = 0; ks < 4; ++ks) {
            int uw = ((ks * 4 + (l >> 4)) ^ (l & 7)) * 8;  // swizzled col
            bf16x8 af[2], bg[2];
            #pragma unroll
            for (int mi = 0; mi < 2; ++mi)
                af[mi] = *(const bf16x8*)&As[wm * 32 + mi * 16 + (l & 15)][uw];
            #pragma unroll
            for (int ni = 0; ni < 2; ++ni)
                bg[ni] = *(const bf16x8*)&Bs[wn * 32 + ni * 16 + (l & 15)][uw];
            #pragma unroll
            for (int mi = 0; mi < 2; ++mi)
                #pragma unroll
                for (int ni = 0; ni < 2; ++ni)
                    acc[mi][ni] = __builtin_amdgcn_mfma_f32_16x16x32_bf16(
                        af[mi], bg[ni], acc[mi][ni], 0, 0, 0);
        }
    }
    #pragma unroll
    for (int mi = 0; mi < 2; ++mi)
        #pragma unroll
        for (int ni = 0; ni < 2; ++ni) {
            int d = n0 + wn * 32 + ni * 16 + (l & 15);
            float bia = bias[d];
            #pragma unroll
            for (int r = 0; r < 4; ++r) {
                int b = b0 + wm * 32 + mi * 16 + (l >> 4) * 4 + r;
                float v = fmaxf(acc[mi][ni][r] + bia, 0.0f);
                fb[(size_t)b * D_F + d] = f2bf(v);
            }
        }
}

// ---------------- K7: big GEMM Z = Linv @ F^T (triangular skip, compute+stage) -
// A = Linv lower-triangular. For K-step k0, rows r < k0 of the A-tile are all
// zero AND never read by the fragment loop (skip condition) -> they are not
// staged either: A-staging volume 32/24/16/8 KB across the 4 K-steps (-37.5%).
__global__ __launch_bounds__(512) void k_gmm(const unsigned short* __restrict__ linv,
                                             const unsigned short* __restrict__ fb,
                                             const float* __restrict__ cpart,
                                             const float* __restrict__ wmix,
                                             const float* __restrict__ ldet,
                                             float* __restrict__ out) {
    __shared__ unsigned short As[256][64];  // 32 KB, swizzled 16B chunks
    __shared__ unsigned short Bs[128][64];  // 16 KB, swizzled
    __shared__ float cb[D_F];
    __shared__ float qpart[4][128];
    int mk = blockIdx.x;
    int b0 = blockIdx.y * 128;
    int tid = threadIdx.x, w = tid >> 6, l = tid & 63;
    int wm = w >> 1, wn = w & 1;
    const unsigned short* Ab = linv + (size_t)mk * D_F * D_F;
    if (tid < D_F) {
        const float* cp = cpart + (size_t)mk * 4 * D_F + tid;
        cb[tid] = cp[0] + cp[256] + cp[512] + cp[768];
    }
    f32x4 acc[4][4] = {};
    for (int k0 = 0; k0 < D_F; k0 += 64) {
        // stage only rows [k0, 256) of A (rows < k0 are zero and never read)
        int nA = 4 - (k0 >> 6);
        for (int it = 0; it < nA; ++it) {
            int o16 = tid + it * 512;
            int r = k0 + (o16 >> 3), c8 = (o16 & 7) ^ (r & 7);
            gload_lds16(Ab + (size_t)r * D_F + k0 + c8 * 8,
                        &As[k0][0] + o16 * 8);
        }
        #pragma unroll
        for (int it = 0; it < 2; ++it) {
            int o16 = tid + it * 512;
            int r = o16 >> 3, c8 = (o16 & 7) ^ (r & 7);
            gload_lds16(fb + (size_t)(b0 + r) * D_F + k0 + c8 * 8, &Bs[0][0] + o16 * 8);
        }
        __syncthreads();
        #pragma unroll
        for (int ks = 0; ks < 2; ++ks) {
            int uw = ((ks * 4 + (l >> 4)) ^ (l & 7)) * 8;  // swizzled col
            bf16x8 bg[4];
            #pragma unroll
            for (int ni = 0; ni < 4; ++ni)
                bg[ni] = *(const bf16x8*)&Bs[wn * 64 + ni * 16 + (l & 15)][uw];
            #pragma unroll
            for (int mi = 0; mi < 4; ++mi) {
                // triangular skip: row group [wm*64+mi*16, +16) has no k in
                // [k0+ks*32, +32) at or below the diagonal when k-range > row_hi
                if (k0 + ks * 32 <= wm * 64 + mi * 16 + 15) {
                    bf16x8 af = *(const bf16x8*)&As[wm * 64 + mi * 16 + (l & 15)][uw];
                    #pragma unroll
                    for (int ni = 0; ni < 4; ++ni)
                        acc[mi][ni] = __builtin_amdgcn_mfma_f32_16x16x32_bf16(
                            af, bg[ni], acc[mi][ni], 0, 0, 0);
                }
            }
        }
        __syncthreads();
    }
    float p[4] = {0, 0, 0, 0};
    #pragma unroll
    for (int mi = 0; mi < 4; ++mi) {
        int ibase = wm * 64 + mi * 16 + ((l >> 4) << 2);
        #pragma unroll
        for (int r = 0; r < 4; ++r) {
            float cv = cb[ibase + r];
            #pragma unroll
            for (int ni = 0; ni < 4; ++ni) {
                float z = acc[mi][ni][r] - cv;
                p[ni] += z * z;
            }
        }
    }
    #pragma unroll
    for (int ni = 0; ni < 4; ++ni) {
        p[ni] += __shfl_xor(p[ni], 16);
        p[ni] += __shfl_xor(p[ni], 32);
    }
    if (l < 16) {
        #pragma unroll
        for (int ni = 0; ni < 4; ++ni)
            qpart[wm][wn * 64 + ni * 16 + l] = p[ni];
    }
    __syncthreads();
    if (tid < 128) {
        float q = qpart[0][tid] + qpart[1][tid] + qpart[2][tid] + qpart[3][tid];
        float lp = -0.5f * (q + (float)D_F * LOG2PI) - ldet[mk];
        out[(size_t)(b0 + tid) * MK + mk] = wmix[mk] * lp;
    }
}

extern "C" void kernel_launch(void* const* d_in, const int* in_sizes, int n_in,
                              void* d_out, int out_size, void* d_ws, size_t ws_size,
                              hipStream_t stream) {
    const float* x     = (const float*)d_in[0];
    const float* W     = (const float*)d_in[1];
    const float* bias  = (const float*)d_in[2];
    const float* means = (const float*)d_in[3];
    const float* covs  = (const float*)d_in[4];
    const float* wts   = (const float*)d_in[5];
    float* out = (float*)d_out;

    char* ws = (char*)d_ws;
    unsigned short* covsb = (unsigned short*)(ws);              // 6.55 MB [mk][10][4096]
    unsigned short* wt    = (unsigned short*)(ws + 6553600);    // 0.5 MB
    unsigned short* fb    = (unsigned short*)(ws + 7077888);    // 2 MB
    unsigned short* linv  = (unsigned short*)(ws + 9175040);    // 10.5 MB
    float* wmix = (float*)(ws + 19742720);                      // 320 B
    float* ldet = (float*)(ws + 19743040);                      // 320 B
    // cpart (320 KB) aliases wt: wt dead after k_feat, cpart written after.
    float* cpart = (float*)(ws + 6553600);

    k_pre<<<dim3(544), dim3(256), 0, stream>>>(W, covs, wts, wt, wmix, ldet, covsb);
    k_feat<<<dim3(64, 4), dim3(256), 0, stream>>>(x, wt, bias, fb);   // last use of wt
    k_inv_panel<<<dim3(MK, 4), dim3(256), 0, stream>>>(covsb, means, linv, cpart);
    k_gmm<<<dim3(MK, 32), dim3(512), 0, stream>>>(linv, fb, cpart, wmix, ldet, out);
}

// Round 16
// 75.402 us; speedup vs baseline: 1.1962x; 1.0439x over previous
//
#include <hip/hip_runtime.h>

#define B_N 4096
#define D_IN 1024
#define D_F 256
#define MK 80
#define LOG2PI 1.8378770664093453f
#define XP_S 72  // padded LDS row stride (bf16 elems)

typedef float f32x4 __attribute__((ext_vector_type(4)));
typedef short bf16x8 __attribute__((ext_vector_type(8)));
typedef float float4_ __attribute__((ext_vector_type(4)));
typedef unsigned int u32x4 __attribute__((ext_vector_type(4)));
typedef unsigned short u16x8 __attribute__((ext_vector_type(8)));

__device__ __forceinline__ unsigned short f2bf(float f) {
    unsigned u = __float_as_uint(f);
    u += 0x7fffu + ((u >> 16) & 1u);
    return (unsigned short)(u >> 16);
}
__device__ __forceinline__ float bf2f(unsigned short h) {
    return __uint_as_float(((unsigned)h) << 16);
}
__device__ __forceinline__ void gload_lds16(const void* g, void* l) {
    __builtin_amdgcn_global_load_lds((const __attribute__((address_space(1))) void*)g,
                                     (__attribute__((address_space(3))) void*)l, 16, 0, 0);
}
__device__ __forceinline__ bf16x8 pack8(float4_ a, float4_ b) {
    bf16x8 r;
    r[0] = (short)f2bf(a.x); r[1] = (short)f2bf(a.y);
    r[2] = (short)f2bf(a.z); r[3] = (short)f2bf(a.w);
    r[4] = (short)f2bf(b.x); r[5] = (short)f2bf(b.y);
    r[6] = (short)f2bf(b.z); r[7] = (short)f2bf(b.w);
    return r;
}

// ---------------- K_pre: W-transpose, stats, covs->bf16, diag-block Neumann ----
// grid 544: [0,64) W-transpose, [64,144) stats, [144,224) off-diag covsb (plain
// bf16 L blocks), [224,544) diag-block inversion (mk,I) via Neumann + MFMA.
// covsb per mk: [0..5] off-diag L(I,K) K<I at idx I*(I-1)/2+K; [6..9] Dinv.
__global__ __launch_bounds__(256) void k_pre(const float* __restrict__ W,
                                             const float* __restrict__ covs,
                                             const float* __restrict__ wts,
                                             unsigned short* __restrict__ wt,
                                             float* __restrict__ wmix,
                                             float* __restrict__ ldet,
                                             unsigned short* __restrict__ covsb) {
    int bx = blockIdx.x, tid = threadIdx.x;
    if (bx < 64) {
        __shared__ unsigned short t[64][65];
        int k0 = (bx >> 2) * 64, n0 = (bx & 3) * 64;
        int r = tid / 64, c = tid % 64;
        #pragma unroll
        for (int rr = r; rr < 64; rr += 4)
            t[rr][c] = f2bf(W[(size_t)(k0 + rr) * D_F + n0 + c]);
        __syncthreads();
        #pragma unroll
        for (int rr = r; rr < 64; rr += 4)
            wt[(size_t)(n0 + rr) * D_IN + k0 + c] = t[c][rr];
    } else if (bx < 144) {
        if (tid < 64) {
            int mk = bx - 64;
            int l = tid;
            const float* Lm = covs + (size_t)mk * D_F * D_F;
            float s = 0.0f;
            for (int i = l; i < D_F; i += 64) s += logf(Lm[(size_t)i * D_F + i]);
            for (int off = 32; off; off >>= 1) s += __shfl_down(s, off);
            if (l == 0) {
                ldet[mk] = s;
                int m = mk / 8, k = mk % 8;
                float mx = -1e30f;
                for (int j = 0; j < 8; j++) mx = fmaxf(mx, wts[m * 8 + j]);
                float sum = 0.0f;
                for (int j = 0; j < 8; j++) sum += expf(wts[m * 8 + j] - mx);
                wmix[mk] = expf(wts[m * 8 + k] - mx) / sum;
            }
        }
    } else if (bx < 224) {
        // covs off-diag lower blocks -> plain bf16: (I,K), K<I, idx = I*(I-1)/2+K
        int mk = bx - 144;
        const float* Cm = covs + (size_t)mk * D_F * D_F;
        unsigned short* Cb = covsb + (size_t)mk * 10 * 4096;
        #pragma unroll
        for (int I = 1; I < 4; ++I)
            for (int K = 0; K < I; ++K) {
                int idx = (I * (I - 1)) / 2 + K;
                for (int t4 = tid; t4 < 1024; t4 += 256) {
                    int r = t4 >> 4, kq = t4 & 15;
                    float4_ v = *(const float4_*)&Cm[(size_t)(I * 64 + r) * D_F
                                                     + K * 64 + kq * 4];
                    ushort4 o;
                    o.x = f2bf(v.x); o.y = f2bf(v.y); o.z = f2bf(v.z); o.w = f2bf(v.w);
                    *(ushort4*)&Cb[(size_t)idx * 4096 + r * 64 + kq * 4] = o;
                }
            }
    } else {
        // diag-block inverse via Neumann: Dinv = (I - X + X^2 - X^3 + X^4) D^-1,
        // X = D^-1 strict_lower(Ldiag), ||X|| ~ 0.08 -> truncation ~3e-6.
        int b = bx - 224;
        int mk = b >> 2, I = b & 3;
        int i0 = I * 64;
        __shared__ float rl[64];
        __shared__ unsigned short X[64][XP_S];
        __shared__ unsigned short Yt[2][64][XP_S];
        int w = tid >> 6, l = tid & 63;
        const float* Cm = covs + (size_t)mk * D_F * D_F;
        if (tid < 64) rl[tid] = 1.0f / Cm[(size_t)(i0 + tid) * D_F + i0 + tid];
        __syncthreads();
        // build X (row-scaled strict lower) directly in LDS
        for (int t4 = tid; t4 < 1024; t4 += 256) {
            int r = t4 >> 4, kq = t4 & 15;
            float4_ v = *(const float4_*)&Cm[(size_t)(i0 + r) * D_F + i0 + kq * 4];
            float ri = rl[r];
            int base = kq * 4;
            ushort4 o;
            o.x = (base     < r) ? f2bf(v.x * ri) : (unsigned short)0;
            o.y = (base + 1 < r) ? f2bf(v.y * ri) : (unsigned short)0;
            o.z = (base + 2 < r) ? f2bf(v.z * ri) : (unsigned short)0;
            o.w = (base + 3 < r) ? f2bf(v.w * ri) : (unsigned short)0;
            *(ushort4*)&X[r][base] = o;
        }
        __syncthreads();
        // T1 = I - X (transposed): Yt[0][j][i] = delta_ij - X[i][j]
        for (int t = tid; t < 4096; t += 256) {
            int j = t >> 6, i = t & 63;
            unsigned short xv = X[i][j];
            Yt[0][j][i] = (i == j) ? (unsigned short)0x3F80
                                   : (unsigned short)(xv ^ 0x8000u);
        }
        __syncthreads();
        int cur = 0;
        for (int it = 0; it < 3; ++it) {
            bf16x8 a0 = *(const bf16x8*)&Yt[cur][16 * w + (l & 15)][(l >> 4) * 8];
            bf16x8 a1 = *(const bf16x8*)&Yt[cur][16 * w + (l & 15)][32 + (l >> 4) * 8];
            f32x4 acc[4] = {{0, 0, 0, 0}, {0, 0, 0, 0}, {0, 0, 0, 0}, {0, 0, 0, 0}};
            #pragma unroll
            for (int ni = 0; ni < 4; ++ni) {
                bf16x8 b0 = *(const bf16x8*)&X[ni * 16 + (l & 15)][(l >> 4) * 8];
                bf16x8 b1 = *(const bf16x8*)&X[ni * 16 + (l & 15)][32 + (l >> 4) * 8];
                acc[ni] = __builtin_amdgcn_mfma_f32_16x16x32_bf16(a0, b0, acc[ni], 0, 0, 0);
                acc[ni] = __builtin_amdgcn_mfma_f32_16x16x32_bf16(a1, b1, acc[ni], 0, 0, 0);
            }
            #pragma unroll
            for (int ni = 0; ni < 4; ++ni)
                #pragma unroll
                for (int q = 0; q < 4; ++q) {
                    int i = ni * 16 + (l & 15);
                    int j = 16 * w + (l >> 4) * 4 + q;
                    float v = ((i == j) ? 1.0f : 0.0f) - acc[ni][q];
                    Yt[cur ^ 1][j][i] = f2bf(v);
                }
            __syncthreads();
            cur ^= 1;
        }
        // Dinv[r][c] = Yt[cur][c][r] * rl[c] -> covsb slot [6+I]
        unsigned short* Xg = covsb + ((size_t)mk * 10 + 6 + I) * 4096;
        for (int t = tid; t < 4096; t += 256) {
            int r = t >> 6, c = t & 63;
            Xg[t] = f2bf(bf2f(Yt[cur][c][r]) * rl[c]);
        }
    }
}

// ---------------- K5b: column panels of Linv via blocked MFMA + cvec partial ---
// St scratch folded into Xp[I] (disjoint lifetimes; St read into regs + one
// extra barrier before the in-place overwrite) -> LDS 83 -> 74 KB, 2 blocks/CU.
// Upper triangle of Lout never written (k_gmm never reads it).
__global__ __launch_bounds__(256) void k_inv_panel(
        const unsigned short* __restrict__ covsb,
        const float* __restrict__ means,
        unsigned short* __restrict__ linv,
        float* __restrict__ cpart) {
    int mk = blockIdx.x, J = blockIdx.y;
    int jc0 = J * 64;
    __shared__ unsigned short Xp[4][64][XP_S];  // 73.7 KB
    __shared__ float muS[64];
    int tid = threadIdx.x, w = tid >> 6, l = tid & 63;
    const unsigned short* Cb = covsb + (size_t)mk * 10 * 4096;   // off-diag [0..5]
    const unsigned short* Dmk = Cb + 6 * 4096;                   // Dinv [6..9]
    unsigned short* Lout = linv + (size_t)mk * D_F * D_F;

    const unsigned short* DJ = Dmk + J * 4096;
    for (int t = tid; t < 4096; t += 256) {
        int r = t >> 6, c = t & 63;
        Xp[J][c][r] = DJ[t];
    }
    for (int t = tid; t < 512; t += 256) {
        int r = t >> 3, s = t & 7;
        ((u32x4*)(Lout + (size_t)(jc0 + r) * D_F + jc0))[s] = ((const u32x4*)(DJ + r * 64))[s];
    }
    __syncthreads();

    for (int I = J + 1; I < 4; ++I) {
        f32x4 acc[4] = {};
        for (int K = J; K < I; ++K) {
            const unsigned short* CB = Cb + (size_t)((I * (I - 1)) / 2 + K) * 4096;
            #pragma unroll
            for (int kb = 0; kb < 2; ++kb) {
                bf16x8 af = *(const bf16x8*)&Xp[K][w * 16 + (l & 15)][kb * 32 + (l >> 4) * 8];
                #pragma unroll
                for (int ni = 0; ni < 4; ++ni) {
                    bf16x8 bf = *(const bf16x8*)&CB[(size_t)(ni * 16 + (l & 15)) * 64
                                                    + kb * 32 + (l >> 4) * 8];
                    acc[ni] = __builtin_amdgcn_mfma_f32_16x16x32_bf16(af, bf, acc[ni], 0, 0, 0);
                }
            }
        }
        // write St (transposed) into Xp[I] (scratch use; final X overwrites below)
        unsigned short(*SbI)[XP_S] = Xp[I];
        #pragma unroll
        for (int ni = 0; ni < 4; ++ni)
            #pragma unroll
            for (int q = 0; q < 4; ++q)
                SbI[w * 16 + ((l >> 4) << 2) + q][ni * 16 + (l & 15)] = f2bf(acc[ni][q]);
        __syncthreads();
        // read St fragments into regs, then barrier so in-place overwrite is safe
        bf16x8 saf0 = *(const bf16x8*)&SbI[w * 16 + (l & 15)][(l >> 4) * 8];
        bf16x8 saf1 = *(const bf16x8*)&SbI[w * 16 + (l & 15)][32 + (l >> 4) * 8];
        __syncthreads();
        f32x4 acc2[4] = {};
        #pragma unroll
        for (int kb = 0; kb < 2; ++kb) {
            bf16x8 af = kb ? saf1 : saf0;
            #pragma unroll
            for (int ni = 0; ni < 4; ++ni) {
                const u16x8* dp = (const u16x8*)(Dmk + (size_t)I * 4096
                                  + (ni * 16 + (l & 15)) * 64 + kb * 32 + (l >> 4) * 8);
                u16x8 dv = *dp ^ (unsigned short)0x8000;  // negate bf16
                bf16x8 bf = __builtin_bit_cast(bf16x8, dv);
                acc2[ni] = __builtin_amdgcn_mfma_f32_16x16x32_bf16(af, bf, acc2[ni], 0, 0, 0);
            }
        }
        #pragma unroll
        for (int ni = 0; ni < 4; ++ni)
            #pragma unroll
            for (int q = 0; q < 4; ++q) {
                int c = w * 16 + ((l >> 4) << 2) + q;
                int r = ni * 16 + (l & 15);
                unsigned short hv = f2bf(acc2[ni][q]);
                Xp[I][c][r] = hv;
                Lout[(size_t)(I * 64 + r) * D_F + jc0 + c] = hv;
            }
        __syncthreads();
    }

    if (tid < 64) muS[tid] = means[(size_t)mk * D_F + jc0 + tid];
    __syncthreads();
    {
        int I = w, r = l;
        float s = 0.0f;
        if (I >= J) {
            for (int c = 0; c < 64; ++c)
                s += bf2f(Xp[I][c][r]) * muS[c];
        }
        cpart[((size_t)mk * 4 + J) * 256 + tid] = s;
    }
}

// ---------------- K4: extractor GEMM, BK=128 (halved barrier count) ------------
__global__ __launch_bounds__(256) void k_feat(const float* __restrict__ x,
                                              const unsigned short* __restrict__ wt,
                                              const float* __restrict__ bias,
                                              unsigned short* __restrict__ fb) {
    __shared__ unsigned short As[64][128];  // 16 KB
    __shared__ unsigned short Bs[64][128];  // 16 KB
    int b0 = blockIdx.x * 64;
    int n0 = blockIdx.y * 64;
    int tid = threadIdx.x, w = tid >> 6, l = tid & 63;
    int wm = w >> 1, wn = w & 1;
    f32x4 acc[2][2] = {};
    for (int k0 = 0; k0 < D_IN; k0 += 128) {
        float4_ av[4][2];
        #pragma unroll
        for (int it = 0; it < 4; ++it) {
            int o16 = tid + it * 256;
            int r = o16 >> 4, c = o16 & 15;
            const float* gp = x + (size_t)(b0 + r) * D_IN + k0 + c * 8;
            av[it][0] = *(const float4_*)gp;
            av[it][1] = *(const float4_*)(gp + 4);
        }
        __syncthreads();  // previous compute done reading LDS
        #pragma unroll
        for (int it = 0; it < 4; ++it) {
            int o16 = tid + it * 256;
            int r = o16 >> 4, c = o16 & 15;
            int cs = c ^ (r & 7);
            *(bf16x8*)&As[r][cs * 8] = pack8(av[it][0], av[it][1]);
            gload_lds16(wt + (size_t)(n0 + r) * D_IN + k0 + cs * 8, &Bs[0][0] + o16 * 8);
        }
        __syncthreads();  // staging complete
        #pragma unroll
        for (int ks = 0; ks < 4; ++ks) {
            int uw = ((ks * 4 + (l >> 4)) ^ (l & 7)) * 8;  // swizzled col
            bf16x8 af[2], bg[2];
            #pragma unroll
            for (int mi = 0; mi < 2; ++mi)
                af[mi] = *(const bf16x8*)&As[wm * 32 + mi * 16 + (l & 15)][uw];
            #pragma unroll
            for (int ni = 0; ni < 2; ++ni)
                bg[ni] = *(const bf16x8*)&Bs[wn * 32 + ni * 16 + (l & 15)][uw];
            #pragma unroll
            for (int mi = 0; mi < 2; ++mi)
                #pragma unroll
                for (int ni = 0; ni < 2; ++ni)
                    acc[mi][ni] = __builtin_amdgcn_mfma_f32_16x16x32_bf16(
                        af[mi], bg[ni], acc[mi][ni], 0, 0, 0);
        }
    }
    #pragma unroll
    for (int mi = 0; mi < 2; ++mi)
        #pragma unroll
        for (int ni = 0; ni < 2; ++ni) {
            int d = n0 + wn * 32 + ni * 16 + (l & 15);
            float bia = bias[d];
            #pragma unroll
            for (int r = 0; r < 4; ++r) {
                int b = b0 + wm * 32 + mi * 16 + (l >> 4) * 4 + r;
                float v = fmaxf(acc[mi][ni][r] + bia, 0.0f);
                fb[(size_t)b * D_F + d] = f2bf(v);
            }
        }
}

// ---------------- K7: big GEMM Z = Linv @ F^T (tri-skip + balanced waves) ------
// Triangular skip (compute + A-staging) as R14/R15, PLUS interleaved row-group
// ownership: wave wm owns 16-row groups {wm, wm+4, wm+8, wm+12} so per-K-step
// skip work is balanced across waves (barrier pace 30 -> 20 MFMA-group units).
__global__ __launch_bounds__(512) void k_gmm(const unsigned short* __restrict__ linv,
                                             const unsigned short* __restrict__ fb,
                                             const float* __restrict__ cpart,
                                             const float* __restrict__ wmix,
                                             const float* __restrict__ ldet,
                                             float* __restrict__ out) {
    __shared__ unsigned short As[256][64];  // 32 KB, swizzled 16B chunks
    __shared__ unsigned short Bs[128][64];  // 16 KB, swizzled
    __shared__ float cb[D_F];
    __shared__ float qpart[4][128];
    int mk = blockIdx.x;
    int b0 = blockIdx.y * 128;
    int tid = threadIdx.x, w = tid >> 6, l = tid & 63;
    int wm = w >> 1, wn = w & 1;
    const unsigned short* Ab = linv + (size_t)mk * D_F * D_F;
    if (tid < D_F) {
        const float* cp = cpart + (size_t)mk * 4 * D_F + tid;
        cb[tid] = cp[0] + cp[256] + cp[512] + cp[768];
    }
    f32x4 acc[4][4] = {};
    for (int k0 = 0; k0 < D_F; k0 += 64) {
        // stage only rows [k0, 256) of A (rows < k0 are zero and never read)
        int nA = 4 - (k0 >> 6);
        for (int it = 0; it < nA; ++it) {
            int o16 = tid + it * 512;
            int r = k0 + (o16 >> 3), c8 = (o16 & 7) ^ (r & 7);
            gload_lds16(Ab + (size_t)r * D_F + k0 + c8 * 8,
                        &As[k0][0] + o16 * 8);
        }
        #pragma unroll
        for (int it = 0; it < 2; ++it) {
            int o16 = tid + it * 512;
            int r = o16 >> 3, c8 = (o16 & 7) ^ (r & 7);
            gload_lds16(fb + (size_t)(b0 + r) * D_F + k0 + c8 * 8, &Bs[0][0] + o16 * 8);
        }
        __syncthreads();
        #pragma unroll
        for (int ks = 0; ks < 2; ++ks) {
            int uw = ((ks * 4 + (l >> 4)) ^ (l & 7)) * 8;  // swizzled col
            bf16x8 bg[4];
            #pragma unroll
            for (int ni = 0; ni < 4; ++ni)
                bg[ni] = *(const bf16x8*)&Bs[wn * 64 + ni * 16 + (l & 15)][uw];
            #pragma unroll
            for (int mi = 0; mi < 4; ++mi) {
                int rbase = (mi * 4 + wm) * 16;  // interleaved row-group ownership
                // triangular skip: group rows [rbase, rbase+15] all-zero over
                // k in [k0+ks*32, +32) when k-range lies above the diagonal
                if (k0 + ks * 32 <= rbase + 15) {
                    bf16x8 af = *(const bf16x8*)&As[rbase + (l & 15)][uw];
                    #pragma unroll
                    for (int ni = 0; ni < 4; ++ni)
                        acc[mi][ni] = __builtin_amdgcn_mfma_f32_16x16x32_bf16(
                            af, bg[ni], acc[mi][ni], 0, 0, 0);
                }
            }
        }
        __syncthreads();
    }
    float p[4] = {0, 0, 0, 0};
    #pragma unroll
    for (int mi = 0; mi < 4; ++mi) {
        int ibase = (mi * 4 + wm) * 16 + ((l >> 4) << 2);
        #pragma unroll
        for (int r = 0; r < 4; ++r) {
            float cv = cb[ibase + r];
            #pragma unroll
            for (int ni = 0; ni < 4; ++ni) {
                float z = acc[mi][ni][r] - cv;
                p[ni] += z * z;
            }
        }
    }
    #pragma unroll
    for (int ni = 0; ni < 4; ++ni) {
        p[ni] += __shfl_xor(p[ni], 16);
        p[ni] += __shfl_xor(p[ni], 32);
    }
    if (l < 16) {
        #pragma unroll
        for (int ni = 0; ni < 4; ++ni)
            qpart[wm][wn * 64 + ni * 16 + l] = p[ni];
    }
    __syncthreads();
    if (tid < 128) {
        float q = qpart[0][tid] + qpart[1][tid] + qpart[2][tid] + qpart[3][tid];
        float lp = -0.5f * (q + (float)D_F * LOG2PI) - ldet[mk];
        out[(size_t)(b0 + tid) * MK + mk] = wmix[mk] * lp;
    }
}

extern "C" void kernel_launch(void* const* d_in, const int* in_sizes, int n_in,
                              void* d_out, int out_size, void* d_ws, size_t ws_size,
                              hipStream_t stream) {
    const float* x     = (const float*)d_in[0];
    const float* W     = (const float*)d_in[1];
    const float* bias  = (const float*)d_in[2];
    const float* means = (const float*)d_in[3];
    const float* covs  = (const float*)d_in[4];
    const float* wts   = (const float*)d_in[5];
    float* out = (float*)d_out;

    char* ws = (char*)d_ws;
    unsigned short* covsb = (unsigned short*)(ws);              // 6.55 MB [mk][10][4096]
    unsigned short* wt    = (unsigned short*)(ws + 6553600);    // 0.5 MB
    unsigned short* fb    = (unsigned short*)(ws + 7077888);    // 2 MB
    unsigned short* linv  = (unsigned short*)(ws + 9175040);    // 10.5 MB
    float* wmix = (float*)(ws + 19742720);                      // 320 B
    float* ldet = (float*)(ws + 19743040);                      // 320 B
    // cpart (320 KB) aliases wt: wt dead after k_feat, cpart written after.
    float* cpart = (float*)(ws + 6553600);

    k_pre<<<dim3(544), dim3(256), 0, stream>>>(W, covs, wts, wt, wmix, ldet, covsb);
    k_feat<<<dim3(64, 4), dim3(256), 0, stream>>>(x, wt, bias, fb);   // last use of wt
    k_inv_panel<<<dim3(MK, 4), dim3(256), 0, stream>>>(covsb, means, linv, cpart);
    k_gmm<<<dim3(MK, 32), dim3(512), 0, stream>>>(linv, fb, cpart, wmix, ldet, out);
}

// Round 17
// 72.449 us; speedup vs baseline: 1.2450x; 1.0408x over previous
//
#include <hip/hip_runtime.h>

#define B_N 4096
#define D_IN 1024
#define D_F 256
#define MK 80
#define LOG2PI 1.8378770664093453f
#define XP_S 72  // padded LDS row stride (bf16 elems)

typedef float f32x4 __attribute__((ext_vector_type(4)));
typedef short bf16x8 __attribute__((ext_vector_type(8)));
typedef float float4_ __attribute__((ext_vector_type(4)));
typedef unsigned int u32x4 __attribute__((ext_vector_type(4)));
typedef unsigned short u16x8 __attribute__((ext_vector_type(8)));

__device__ __forceinline__ unsigned short f2bf(float f) {
    unsigned u = __float_as_uint(f);
    u += 0x7fffu + ((u >> 16) & 1u);
    return (unsigned short)(u >> 16);
}
__device__ __forceinline__ float bf2f(unsigned short h) {
    return __uint_as_float(((unsigned)h) << 16);
}
__device__ __forceinline__ void gload_lds16(const void* g, void* l) {
    __builtin_amdgcn_global_load_lds((const __attribute__((address_space(1))) void*)g,
                                     (__attribute__((address_space(3))) void*)l, 16, 0, 0);
}
__device__ __forceinline__ bf16x8 pack8(float4_ a, float4_ b) {
    bf16x8 r;
    r[0] = (short)f2bf(a.x); r[1] = (short)f2bf(a.y);
    r[2] = (short)f2bf(a.z); r[3] = (short)f2bf(a.w);
    r[4] = (short)f2bf(b.x); r[5] = (short)f2bf(b.y);
    r[6] = (short)f2bf(b.z); r[7] = (short)f2bf(b.w);
    return r;
}

// ---------------- K_pre: W-transpose, stats, covs->bf16, diag-block Neumann ----
// grid 944: [0,64) W-transpose, [64,144) stats, [144,624) off-diag conversion
// (480 fine blocks: one per (mk, off-diag block)), [624,944) diag-block
// inversion (mk,I) via Neumann (degree 3) + MFMA.
// covsb per mk: [0..5] off-diag L(I,K) K<I at idx I*(I-1)/2+K; [6..9] Dinv.
__global__ __launch_bounds__(256) void k_pre(const float* __restrict__ W,
                                             const float* __restrict__ covs,
                                             const float* __restrict__ wts,
                                             unsigned short* __restrict__ wt,
                                             float* __restrict__ wmix,
                                             float* __restrict__ ldet,
                                             unsigned short* __restrict__ covsb) {
    int bx = blockIdx.x, tid = threadIdx.x;
    if (bx < 64) {
        __shared__ unsigned short t[64][65];
        int k0 = (bx >> 2) * 64, n0 = (bx & 3) * 64;
        int r = tid / 64, c = tid % 64;
        #pragma unroll
        for (int rr = r; rr < 64; rr += 4)
            t[rr][c] = f2bf(W[(size_t)(k0 + rr) * D_F + n0 + c]);
        __syncthreads();
        #pragma unroll
        for (int rr = r; rr < 64; rr += 4)
            wt[(size_t)(n0 + rr) * D_IN + k0 + c] = t[c][rr];
    } else if (bx < 144) {
        if (tid < 64) {
            int mk = bx - 64;
            int l = tid;
            const float* Lm = covs + (size_t)mk * D_F * D_F;
            float s = 0.0f;
            for (int i = l; i < D_F; i += 64) s += logf(Lm[(size_t)i * D_F + i]);
            for (int off = 32; off; off >>= 1) s += __shfl_down(s, off);
            if (l == 0) {
                ldet[mk] = s;
                int m = mk / 8, k = mk % 8;
                float mx = -1e30f;
                for (int j = 0; j < 8; j++) mx = fmaxf(mx, wts[m * 8 + j]);
                float sum = 0.0f;
                for (int j = 0; j < 8; j++) sum += expf(wts[m * 8 + j] - mx);
                wmix[mk] = expf(wts[m * 8 + k] - mx) / sum;
            }
        }
    } else if (bx < 624) {
        // one off-diag 64x64 block per CTA: b -> (mk, idx), idx -> (I,K)
        int b = bx - 144;
        int mk = b / 6, idx = b % 6;
        int I = (idx < 1) ? 1 : (idx < 3) ? 2 : 3;
        int K = idx - (I * (I - 1)) / 2;
        const float* Cm = covs + (size_t)mk * D_F * D_F;
        unsigned short* Cb = covsb + ((size_t)mk * 10 + idx) * 4096;
        #pragma unroll
        for (int t4 = tid; t4 < 1024; t4 += 256) {
            int r = t4 >> 4, kq = t4 & 15;
            float4_ v = *(const float4_*)&Cm[(size_t)(I * 64 + r) * D_F
                                             + K * 64 + kq * 4];
            ushort4 o;
            o.x = f2bf(v.x); o.y = f2bf(v.y); o.z = f2bf(v.z); o.w = f2bf(v.w);
            *(ushort4*)&Cb[r * 64 + kq * 4] = o;
        }
    } else {
        // diag-block inverse via Neumann degree 3: Dinv = (I - X + X^2 - X^3) D^-1,
        // X = D^-1 strict_lower(Ldiag), ||X|| ~ 0.16 -> truncation ||X^4|| ~ 6e-4,
        // an order below bf16 rounding (4e-3) which dominates the error budget.
        int b = bx - 624;
        int mk = b >> 2, I = b & 3;
        int i0 = I * 64;
        __shared__ float rl[64];
        __shared__ unsigned short X[64][XP_S];
        __shared__ unsigned short Yt[2][64][XP_S];
        int w = tid >> 6, l = tid & 63;
        const float* Cm = covs + (size_t)mk * D_F * D_F;
        if (tid < 64) rl[tid] = 1.0f / Cm[(size_t)(i0 + tid) * D_F + i0 + tid];
        __syncthreads();
        // build X (row-scaled strict lower) directly in LDS
        for (int t4 = tid; t4 < 1024; t4 += 256) {
            int r = t4 >> 4, kq = t4 & 15;
            float4_ v = *(const float4_*)&Cm[(size_t)(i0 + r) * D_F + i0 + kq * 4];
            float ri = rl[r];
            int base = kq * 4;
            ushort4 o;
            o.x = (base     < r) ? f2bf(v.x * ri) : (unsigned short)0;
            o.y = (base + 1 < r) ? f2bf(v.y * ri) : (unsigned short)0;
            o.z = (base + 2 < r) ? f2bf(v.z * ri) : (unsigned short)0;
            o.w = (base + 3 < r) ? f2bf(v.w * ri) : (unsigned short)0;
            *(ushort4*)&X[r][base] = o;
        }
        __syncthreads();
        // T1 = I - X (transposed): Yt[0][j][i] = delta_ij - X[i][j]
        for (int t = tid; t < 4096; t += 256) {
            int j = t >> 6, i = t & 63;
            unsigned short xv = X[i][j];
            Yt[0][j][i] = (i == j) ? (unsigned short)0x3F80
                                   : (unsigned short)(xv ^ 0x8000u);
        }
        __syncthreads();
        int cur = 0;
        for (int it = 0; it < 2; ++it) {  // 2 Horner steps -> degree 3
            bf16x8 a0 = *(const bf16x8*)&Yt[cur][16 * w + (l & 15)][(l >> 4) * 8];
            bf16x8 a1 = *(const bf16x8*)&Yt[cur][16 * w + (l & 15)][32 + (l >> 4) * 8];
            f32x4 acc[4] = {{0, 0, 0, 0}, {0, 0, 0, 0}, {0, 0, 0, 0}, {0, 0, 0, 0}};
            #pragma unroll
            for (int ni = 0; ni < 4; ++ni) {
                bf16x8 b0 = *(const bf16x8*)&X[ni * 16 + (l & 15)][(l >> 4) * 8];
                bf16x8 b1 = *(const bf16x8*)&X[ni * 16 + (l & 15)][32 + (l >> 4) * 8];
                acc[ni] = __builtin_amdgcn_mfma_f32_16x16x32_bf16(a0, b0, acc[ni], 0, 0, 0);
                acc[ni] = __builtin_amdgcn_mfma_f32_16x16x32_bf16(a1, b1, acc[ni], 0, 0, 0);
            }
            #pragma unroll
            for (int ni = 0; ni < 4; ++ni)
                #pragma unroll
                for (int q = 0; q < 4; ++q) {
                    int i = ni * 16 + (l & 15);
                    int j = 16 * w + (l >> 4) * 4 + q;
                    float v = ((i == j) ? 1.0f : 0.0f) - acc[ni][q];
                    Yt[cur ^ 1][j][i] = f2bf(v);
                }
            __syncthreads();
            cur ^= 1;
        }
        // Dinv[r][c] = Yt[cur][c][r] * rl[c] -> covsb slot [6+I]
        unsigned short* Xg = covsb + ((size_t)mk * 10 + 6 + I) * 4096;
        for (int t = tid; t < 4096; t += 256) {
            int r = t >> 6, c = t & 63;
            Xg[t] = f2bf(bf2f(Yt[cur][c][r]) * rl[c]);
        }
    }
}

// ---------------- K5b: column panels of Linv via blocked MFMA + cvec partial ---
// St scratch folded into Xp[I] (disjoint lifetimes; St read into regs + one
// extra barrier before the in-place overwrite) -> LDS 74 KB, 2 blocks/CU.
// Upper triangle of Lout never written (k_gmm never reads it).
__global__ __launch_bounds__(256) void k_inv_panel(
        const unsigned short* __restrict__ covsb,
        const float* __restrict__ means,
        unsigned short* __restrict__ linv,
        float* __restrict__ cpart) {
    int mk = blockIdx.x, J = blockIdx.y;
    int jc0 = J * 64;
    __shared__ unsigned short Xp[4][64][XP_S];  // 73.7 KB
    __shared__ float muS[64];
    int tid = threadIdx.x, w = tid >> 6, l = tid & 63;
    const unsigned short* Cb = covsb + (size_t)mk * 10 * 4096;   // off-diag [0..5]
    const unsigned short* Dmk = Cb + 6 * 4096;                   // Dinv [6..9]
    unsigned short* Lout = linv + (size_t)mk * D_F * D_F;

    const unsigned short* DJ = Dmk + J * 4096;
    for (int t = tid; t < 4096; t += 256) {
        int r = t >> 6, c = t & 63;
        Xp[J][c][r] = DJ[t];
    }
    for (int t = tid; t < 512; t += 256) {
        int r = t >> 3, s = t & 7;
        ((u32x4*)(Lout + (size_t)(jc0 + r) * D_F + jc0))[s] = ((const u32x4*)(DJ + r * 64))[s];
    }
    __syncthreads();

    for (int I = J + 1; I < 4; ++I) {
        f32x4 acc[4] = {};
        for (int K = J; K < I; ++K) {
            const unsigned short* CB = Cb + (size_t)((I * (I - 1)) / 2 + K) * 4096;
            #pragma unroll
            for (int kb = 0; kb < 2; ++kb) {
                bf16x8 af = *(const bf16x8*)&Xp[K][w * 16 + (l & 15)][kb * 32 + (l >> 4) * 8];
                #pragma unroll
                for (int ni = 0; ni < 4; ++ni) {
                    bf16x8 bf = *(const bf16x8*)&CB[(size_t)(ni * 16 + (l & 15)) * 64
                                                    + kb * 32 + (l >> 4) * 8];
                    acc[ni] = __builtin_amdgcn_mfma_f32_16x16x32_bf16(af, bf, acc[ni], 0, 0, 0);
                }
            }
        }
        // write St (transposed) into Xp[I] (scratch use; final X overwrites below)
        unsigned short(*SbI)[XP_S] = Xp[I];
        #pragma unroll
        for (int ni = 0; ni < 4; ++ni)
            #pragma unroll
            for (int q = 0; q < 4; ++q)
                SbI[w * 16 + ((l >> 4) << 2) + q][ni * 16 + (l & 15)] = f2bf(acc[ni][q]);
        __syncthreads();
        // read St fragments into regs, then barrier so in-place overwrite is safe
        bf16x8 saf0 = *(const bf16x8*)&SbI[w * 16 + (l & 15)][(l >> 4) * 8];
        bf16x8 saf1 = *(const bf16x8*)&SbI[w * 16 + (l & 15)][32 + (l >> 4) * 8];
        __syncthreads();
        f32x4 acc2[4] = {};
        #pragma unroll
        for (int kb = 0; kb < 2; ++kb) {
            bf16x8 af = kb ? saf1 : saf0;
            #pragma unroll
            for (int ni = 0; ni < 4; ++ni) {
                const u16x8* dp = (const u16x8*)(Dmk + (size_t)I * 4096
                                  + (ni * 16 + (l & 15)) * 64 + kb * 32 + (l >> 4) * 8);
                u16x8 dv = *dp ^ (unsigned short)0x8000;  // negate bf16
                bf16x8 bf = __builtin_bit_cast(bf16x8, dv);
                acc2[ni] = __builtin_amdgcn_mfma_f32_16x16x32_bf16(af, bf, acc2[ni], 0, 0, 0);
            }
        }
        #pragma unroll
        for (int ni = 0; ni < 4; ++ni)
            #pragma unroll
            for (int q = 0; q < 4; ++q) {
                int c = w * 16 + ((l >> 4) << 2) + q;
                int r = ni * 16 + (l & 15);
                unsigned short hv = f2bf(acc2[ni][q]);
                Xp[I][c][r] = hv;
                Lout[(size_t)(I * 64 + r) * D_F + jc0 + c] = hv;
            }
        __syncthreads();
    }

    if (tid < 64) muS[tid] = means[(size_t)mk * D_F + jc0 + tid];
    __syncthreads();
    {
        int I = w, r = l;
        float s = 0.0f;
        if (I >= J) {
            for (int c = 0; c < 64; ++c)
                s += bf2f(Xp[I][c][r]) * muS[c];
        }
        cpart[((size_t)mk * 4 + J) * 256 + tid] = s;
    }
}

// ---------------- K4: extractor GEMM, BK=128 (halved barrier count) ------------
__global__ __launch_bounds__(256) void k_feat(const float* __restrict__ x,
                                              const unsigned short* __restrict__ wt,
                                              const float* __restrict__ bias,
                                              unsigned short* __restrict__ fb) {
    __shared__ unsigned short As[64][128];  // 16 KB
    __shared__ unsigned short Bs[64][128];  // 16 KB
    int b0 = blockIdx.x * 64;
    int n0 = blockIdx.y * 64;
    int tid = threadIdx.x, w = tid >> 6, l = tid & 63;
    int wm = w >> 1, wn = w & 1;
    f32x4 acc[2][2] = {};
    for (int k0 = 0; k0 < D_IN; k0 += 128) {
        float4_ av[4][2];
        #pragma unroll
        for (int it = 0; it < 4; ++it) {
            int o16 = tid + it * 256;
            int r = o16 >> 4, c = o16 & 15;
            const float* gp = x + (size_t)(b0 + r) * D_IN + k0 + c * 8;
            av[it][0] = *(const float4_*)gp;
            av[it][1] = *(const float4_*)(gp + 4);
        }
        __syncthreads();  // previous compute done reading LDS
        #pragma unroll
        for (int it = 0; it < 4; ++it) {
            int o16 = tid + it * 256;
            int r = o16 >> 4, c = o16 & 15;
            int cs = c ^ (r & 7);
            *(bf16x8*)&As[r][cs * 8] = pack8(av[it][0], av[it][1]);
            gload_lds16(wt + (size_t)(n0 + r) * D_IN + k0 + cs * 8, &Bs[0][0] + o16 * 8);
        }
        __syncthreads();  // staging complete
        #pragma unroll
        for (int ks = 0; ks < 4; ++ks) {
            int uw = ((ks * 4 + (l >> 4)) ^ (l & 7)) * 8;  // swizzled col
            bf16x8 af[2], bg[2];
            #pragma unroll
            for (int mi = 0; mi < 2; ++mi)
                af[mi] = *(const bf16x8*)&As[wm * 32 + mi * 16 + (l & 15)][uw];
            #pragma unroll
            for (int ni = 0; ni < 2; ++ni)
                bg[ni] = *(const bf16x8*)&Bs[wn * 32 + ni * 16 + (l & 15)][uw];
            #pragma unroll
            for (int mi = 0; mi < 2; ++mi)
                #pragma unroll
                for (int ni = 0; ni < 2; ++ni)
                    acc[mi][ni] = __builtin_amdgcn_mfma_f32_16x16x32_bf16(
                        af[mi], bg[ni], acc[mi][ni], 0, 0, 0);
        }
    }
    #pragma unroll
    for (int mi = 0; mi < 2; ++mi)
        #pragma unroll
        for (int ni = 0; ni < 2; ++ni) {
            int d = n0 + wn * 32 + ni * 16 + (l & 15);
            float bia = bias[d];
            #pragma unroll
            for (int r = 0; r < 4; ++r) {
                int b = b0 + wm * 32 + mi * 16 + (l >> 4) * 4 + r;
                float v = fmaxf(acc[mi][ni][r] + bia, 0.0f);
                fb[(size_t)b * D_F + d] = f2bf(v);
            }
        }
}

// ---------------- K7: big GEMM Z = Linv @ F^T (tri-skip + balanced waves) ------
// Triangular skip (compute + A-staging) + interleaved row-group ownership:
// wave wm owns 16-row groups {wm, wm+4, wm+8, wm+12} so per-K-step skip work
// is balanced across waves.
__global__ __launch_bounds__(512) void k_gmm(const unsigned short* __restrict__ linv,
                                             const unsigned short* __restrict__ fb,
                                             const float* __restrict__ cpart,
                                             const float* __restrict__ wmix,
                                             const float* __restrict__ ldet,
                                             float* __restrict__ out) {
    __shared__ unsigned short As[256][64];  // 32 KB, swizzled 16B chunks
    __shared__ unsigned short Bs[128][64];  // 16 KB, swizzled
    __shared__ float cb[D_F];
    __shared__ float qpart[4][128];
    int mk = blockIdx.x;
    int b0 = blockIdx.y * 128;
    int tid = threadIdx.x, w = tid >> 6, l = tid & 63;
    int wm = w >> 1, wn = w & 1;
    const unsigned short* Ab = linv + (size_t)mk * D_F * D_F;
    if (tid < D_F) {
        const float* cp = cpart + (size_t)mk * 4 * D_F + tid;
        cb[tid] = cp[0] + cp[256] + cp[512] + cp[768];
    }
    f32x4 acc[4][4] = {};
    for (int k0 = 0; k0 < D_F; k0 += 64) {
        // stage only rows [k0, 256) of A (rows < k0 are zero and never read)
        int nA = 4 - (k0 >> 6);
        for (int it = 0; it < nA; ++it) {
            int o16 = tid + it * 512;
            int r = k0 + (o16 >> 3), c8 = (o16 & 7) ^ (r & 7);
            gload_lds16(Ab + (size_t)r * D_F + k0 + c8 * 8,
                        &As[k0][0] + o16 * 8);
        }
        #pragma unroll
        for (int it = 0; it < 2; ++it) {
            int o16 = tid + it * 512;
            int r = o16 >> 3, c8 = (o16 & 7) ^ (r & 7);
            gload_lds16(fb + (size_t)(b0 + r) * D_F + k0 + c8 * 8, &Bs[0][0] + o16 * 8);
        }
        __syncthreads();
        #pragma unroll
        for (int ks = 0; ks < 2; ++ks) {
            int uw = ((ks * 4 + (l >> 4)) ^ (l & 7)) * 8;  // swizzled col
            bf16x8 bg[4];
            #pragma unroll
            for (int ni = 0; ni < 4; ++ni)
                bg[ni] = *(const bf16x8*)&Bs[wn * 64 + ni * 16 + (l & 15)][uw];
            #pragma unroll
            for (int mi = 0; mi < 4; ++mi) {
                int rbase = (mi * 4 + wm) * 16;  // interleaved row-group ownership
                if (k0 + ks * 32 <= rbase + 15) {
                    bf16x8 af = *(const bf16x8*)&As[rbase + (l & 15)][uw];
                    #pragma unroll
                    for (int ni = 0; ni < 4; ++ni)
                        acc[mi][ni] = __builtin_amdgcn_mfma_f32_16x16x32_bf16(
                            af, bg[ni], acc[mi][ni], 0, 0, 0);
                }
            }
        }
        __syncthreads();
    }
    float p[4] = {0, 0, 0, 0};
    #pragma unroll
    for (int mi = 0; mi < 4; ++mi) {
        int ibase = (mi * 4 + wm) * 16 + ((l >> 4) << 2);
        #pragma unroll
        for (int r = 0; r < 4; ++r) {
            float cv = cb[ibase + r];
            #pragma unroll
            for (int ni = 0; ni < 4; ++ni) {
                float z = acc[mi][ni][r] - cv;
                p[ni] += z * z;
            }
        }
    }
    #pragma unroll
    for (int ni = 0; ni < 4; ++ni) {
        p[ni] += __shfl_xor(p[ni], 16);
        p[ni] += __shfl_xor(p[ni], 32);
    }
    if (l < 16) {
        #pragma unroll
        for (int ni = 0; ni < 4; ++ni)
            qpart[wm][wn * 64 + ni * 16 + l] = p[ni];
    }
    __syncthreads();
    if (tid < 128) {
        float q = qpart[0][tid] + qpart[1][tid] + qpart[2][tid] + qpart[3][tid];
        float lp = -0.5f * (q + (float)D_F * LOG2PI) - ldet[mk];
        out[(size_t)(b0 + tid) * MK + mk] = wmix[mk] * lp;
    }
}

extern "C" void kernel_launch(void* const* d_in, const int* in_sizes, int n_in,
                              void* d_out, int out_size, void* d_ws, size_t ws_size,
                              hipStream_t stream) {
    const float* x     = (const float*)d_in[0];
    const float* W     = (const float*)d_in[1];
    const float* bias  = (const float*)d_in[2];
    const float* means = (const float*)d_in[3];
    const float* covs  = (const float*)d_in[4];
    const float* wts   = (const float*)d_in[5];
    float* out = (float*)d_out;

    char* ws = (char*)d_ws;
    unsigned short* covsb = (unsigned short*)(ws);              // 6.55 MB [mk][10][4096]
    unsigned short* wt    = (unsigned short*)(ws + 6553600);    // 0.5 MB
    unsigned short* fb    = (unsigned short*)(ws + 7077888);    // 2 MB
    unsigned short* linv  = (unsigned short*)(ws + 9175040);    // 10.5 MB
    float* wmix = (float*)(ws + 19742720);                      // 320 B
    float* ldet = (float*)(ws + 19743040);                      // 320 B
    // cpart (320 KB) aliases wt: wt dead after k_feat, cpart written after.
    float* cpart = (float*)(ws + 6553600);

    k_pre<<<dim3(944), dim3(256), 0, stream>>>(W, covs, wts, wt, wmix, ldet, covsb);
    k_feat<<<dim3(64, 4), dim3(256), 0, stream>>>(x, wt, bias, fb);   // last use of wt
    k_inv_panel<<<dim3(MK, 4), dim3(256), 0, stream>>>(covsb, means, linv, cpart);
    k_gmm<<<dim3(MK, 32), dim3(512), 0, stream>>>(linv, fb, cpart, wmix, ldet, out);
}